// Round 1
// baseline (1210.719 us; speedup 1.0000x reference)
//
#include <hip/hip_runtime.h>
#include <hip/hip_bf16.h>

#define N_NODES 3000
#define T_STEPS 64
#define D_DYN   5
#define POP     16
#define DEMO    32
#define ECO     16
#define R       128
#define Z4      512      // 4*R
#define SLOPE   0.01f

#define ROWS    12
#define NBLK    (N_NODES / ROWS)   // 250

// ---- workspace layout (floats) ----
#define WS_S1P 0
#define WS_S1D 3000
#define WS_S1E 6000
#define WS_S2P 9000
#define WS_S2D 12000
#define WS_S2E 15000
#define WS_GV  18000      // 2 floats
#define WS_ATT 18432      // 3000
#define WS_XW  21504      // N*T*5 = 960000
// total ~981504 floats = 3.93 MB

// ---- output layout (floats, concat in return order) ----
#define OUT_Y    0               // N*T = 192000
#define OUT_DIST 192000          // N*N = 9000000
#define OUT_TW   9192000         // N*T*5 = 960000
#define OUT_HT   10152000        // N*R = 384000
#define OUT_CT   10536000        // N*R = 384000

__device__ __forceinline__ float sigf(float x)   { return 1.0f / (1.0f + __expf(-x)); }
__device__ __forceinline__ float leakyf(float x) { return x >= 0.0f ? x : SLOPE * x; }

// ---------------------------------------------------------------------------
// Kernel 1: per-node pair-score vectors s1/s2 for pop/demo/eco, plus geo vec
// ---------------------------------------------------------------------------
__global__ __launch_bounds__(256) void scores_kernel(
    const float* __restrict__ pop,  const float* __restrict__ demo,
    const float* __restrict__ eco,
    const float* __restrict__ W_pop,  const float* __restrict__ a_pop,
    const float* __restrict__ W_demo, const float* __restrict__ a_demo,
    const float* __restrict__ W_eco,  const float* __restrict__ a_eco,
    const float* __restrict__ W_geo,  const float* __restrict__ a_geo,
    float* __restrict__ ws)
{
  int i = blockIdx.x * blockDim.x + threadIdx.x;
  if (i == 0) {
    float a0 = a_geo[0], a1 = a_geo[1];
    ws[WS_GV + 0] = W_geo[0] * a0 + W_geo[1] * a1;
    ws[WS_GV + 1] = W_geo[2] * a0 + W_geo[3] * a1;
  }
  if (i >= N_NODES) return;

  { // pop (16)
    float x[POP];
#pragma unroll
    for (int k = 0; k < POP; k++) x[k] = pop[i * POP + k];
    float s1 = 0.f, s2 = 0.f;
#pragma unroll
    for (int r = 0; r < POP; r++) {
      float h = 0.f;
#pragma unroll
      for (int k = 0; k < POP; k++) h = fmaf(x[k], W_pop[k * POP + r], h);
      s1 = fmaf(h, a_pop[r], s1);
      s2 = fmaf(h, a_pop[POP + r], s2);
    }
    ws[WS_S1P + i] = s1; ws[WS_S2P + i] = s2;
  }
  { // demo (32)
    float x[DEMO];
#pragma unroll
    for (int k = 0; k < DEMO; k++) x[k] = demo[i * DEMO + k];
    float s1 = 0.f, s2 = 0.f;
#pragma unroll 4
    for (int r = 0; r < DEMO; r++) {
      float h = 0.f;
#pragma unroll
      for (int k = 0; k < DEMO; k++) h = fmaf(x[k], W_demo[k * DEMO + r], h);
      s1 = fmaf(h, a_demo[r], s1);
      s2 = fmaf(h, a_demo[DEMO + r], s2);
    }
    ws[WS_S1D + i] = s1; ws[WS_S2D + i] = s2;
  }
  { // eco (16)
    float x[ECO];
#pragma unroll
    for (int k = 0; k < ECO; k++) x[k] = eco[i * ECO + k];
    float s1 = 0.f, s2 = 0.f;
#pragma unroll
    for (int r = 0; r < ECO; r++) {
      float h = 0.f;
#pragma unroll
      for (int k = 0; k < ECO; k++) h = fmaf(x[k], W_eco[k * ECO + r], h);
      s1 = fmaf(h, a_eco[r], s1);
      s2 = fmaf(h, a_eco[ECO + r], s2);
    }
    ws[WS_S1E + i] = s1; ws[WS_S2E + i] = s2;
  }
}

// ---------------------------------------------------------------------------
// Kernel 2: gate MLPs -> total_weights (out) and xw = tw*dynamic (ws)
// ---------------------------------------------------------------------------
__global__ __launch_bounds__(256) void weights_kernel(
    const float* __restrict__ dyn,
    const float* __restrict__ cw_w1, const float* __restrict__ cw_b1,
    const float* __restrict__ cw_w2, const float* __restrict__ cw_b2,
    const float* __restrict__ hw_w1, const float* __restrict__ hw_b1,
    const float* __restrict__ hw_w2, const float* __restrict__ hw_b2,
    float* __restrict__ out, float* __restrict__ ws)
{
  __shared__ float s_cw1[R], s_cb1[R], s_cw2[R], s_hb1[R];
  __shared__ float s_hw1[4 * R], s_hw2[R * 4];
  int tid = threadIdx.x;
  if (tid < R) {
    s_cw1[tid] = cw_w1[tid]; s_cb1[tid] = cw_b1[tid];
    s_cw2[tid] = cw_w2[tid]; s_hb1[tid] = hw_b1[tid];
  }
  for (int i = tid; i < 4 * R; i += 256) { s_hw1[i] = hw_w1[i]; s_hw2[i] = hw_w2[i]; }
  __syncthreads();

  int idx = blockIdx.x * 256 + tid;          // 0..191999 (grid exact)
  float x0 = dyn[idx * 5 + 0], x1 = dyn[idx * 5 + 1], x2 = dyn[idx * 5 + 2];
  float x3 = dyn[idx * 5 + 3], x4 = dyn[idx * 5 + 4];

  float acc = 0.f, o0 = 0.f, o1 = 0.f, o2 = 0.f, o3 = 0.f;
#pragma unroll 8
  for (int r = 0; r < R; r++) {
    float u = leakyf(fmaf(x0, s_cw1[r], s_cb1[r]));
    acc = fmaf(u, s_cw2[r], acc);
    float v = s_hb1[r];
    v = fmaf(x1, s_hw1[r], v);
    v = fmaf(x2, s_hw1[R + r], v);
    v = fmaf(x3, s_hw1[2 * R + r], v);
    v = fmaf(x4, s_hw1[3 * R + r], v);
    v = leakyf(v);
    o0 = fmaf(v, s_hw2[r * 4 + 0], o0);
    o1 = fmaf(v, s_hw2[r * 4 + 1], o1);
    o2 = fmaf(v, s_hw2[r * 4 + 2], o2);
    o3 = fmaf(v, s_hw2[r * 4 + 3], o3);
  }
  float tw0 = sigf(acc + cw_b2[0]);
  float tw1 = sigf(o0 + hw_b2[0]);
  float tw2 = sigf(o1 + hw_b2[1]);
  float tw3 = sigf(o2 + hw_b2[2]);
  float tw4 = sigf(o3 + hw_b2[3]);

  out[OUT_TW + idx * 5 + 0] = tw0;
  out[OUT_TW + idx * 5 + 1] = tw1;
  out[OUT_TW + idx * 5 + 2] = tw2;
  out[OUT_TW + idx * 5 + 3] = tw3;
  out[OUT_TW + idx * 5 + 4] = tw4;

  ws[WS_XW + idx * 5 + 0] = tw0 * x0;
  ws[WS_XW + idx * 5 + 1] = tw1 * x1;
  ws[WS_XW + idx * 5 + 2] = tw2 * x2;
  ws[WS_XW + idx * 5 + 3] = tw3 * x3;
  ws[WS_XW + idx * 5 + 4] = tw4 * x4;
}

// ---------------------------------------------------------------------------
// Kernel 3: dist rows (4 sigmoids + row softmax) + att_scale = 1 + rowsum
// ---------------------------------------------------------------------------
__global__ __launch_bounds__(256) void dist_kernel(
    const float* __restrict__ geo, float* __restrict__ out, float* __restrict__ ws)
{
  int i = blockIdx.x;
  int tid = threadIdx.x;
  __shared__ float sm[20];

  float s1p = ws[WS_S1P + i], s1d = ws[WS_S1D + i], s1e = ws[WS_S1E + i];
  float gv0 = ws[WS_GV + 0], gv1 = ws[WS_GV + 1];

  float vals[12];
  float vmax = -3.0e38f;
  int cnt = 0;
  for (int j = tid; j < N_NODES; j += 256) {
    float2 g = *(const float2*)&geo[((size_t)i * N_NODES + j) * 2];
    float v = sigf(s1p + ws[WS_S2P + j]) + sigf(s1d + ws[WS_S2D + j]) +
              sigf(s1e + ws[WS_S2E + j]) + sigf(fmaf(g.x, gv0, g.y * gv1));
    vals[cnt++] = v;
    vmax = fmaxf(vmax, v);
  }
  int wid = tid >> 6, lane = tid & 63;
  for (int off = 32; off; off >>= 1) vmax = fmaxf(vmax, __shfl_down(vmax, off, 64));
  if (lane == 0) sm[wid] = vmax;
  __syncthreads();
  if (tid == 0) sm[8] = fmaxf(fmaxf(sm[0], sm[1]), fmaxf(sm[2], sm[3]));
  __syncthreads();
  vmax = sm[8];

  float lsum = 0.f;
  for (int k = 0; k < cnt; k++) { float e = __expf(vals[k] - vmax); vals[k] = e; lsum += e; }
  for (int off = 32; off; off >>= 1) lsum += __shfl_down(lsum, off, 64);
  if (lane == 0) sm[4 + wid] = lsum;
  __syncthreads();
  if (tid == 0) sm[9] = sm[4] + sm[5] + sm[6] + sm[7];
  __syncthreads();
  float inv = 1.0f / sm[9];

  float rs = 0.f;
  cnt = 0;
  for (int j = tid; j < N_NODES; j += 256) {
    float w = vals[cnt++] * inv;
    out[OUT_DIST + (size_t)i * N_NODES + j] = w;
    rs += w;
  }
  for (int off = 32; off; off >>= 1) rs += __shfl_down(rs, off, 64);
  if (lane == 0) sm[10 + wid] = rs;
  __syncthreads();
  if (tid == 0) ws[WS_ATT + i] = 1.0f + (sm[10] + sm[11] + sm[12] + sm[13]);
}

// ---------------------------------------------------------------------------
// Kernel 4: persistent fused LSTM (64 steps) + attention-scaled head -> y,hT,cT
// 250 blocks x 256 threads; block owns 12 rows for the whole sequence.
// LDS: lin_w (64KB) + h/c (12KB) + z (24KB) + small = ~102KB dynamic.
// ---------------------------------------------------------------------------
__global__ __launch_bounds__(256) void lstm_kernel(
    const float* __restrict__ Wih, const float* __restrict__ Whh,
    const float* __restrict__ b_lstm,
    const float* __restrict__ lin_w, const float* __restrict__ lin_b,
    const float* __restrict__ lin2_w, const float* __restrict__ lin2_b,
    const float* __restrict__ ws, float* __restrict__ out)
{
  extern __shared__ float sm[];
  float* lw_s    = sm;                       // 16384  lin_w [k*128 + c]
  float* h_s     = lw_s + 16384;             // 12*128
  float* c_s     = h_s + ROWS * R;           // 12*128
  float* z_s     = c_s + ROWS * R;           // 12*512
  float* xw_s    = z_s + ROWS * Z4;          // 12*8 (pad 5->8)
  float* scale_s = xw_s + ROWS * 8;          // 16
  float* linb_s  = scale_s + 16;             // 128
  float* lin2_s  = linb_s + R;               // 128

  int tid = threadIdx.x;
  int row0 = blockIdx.x * ROWS;
  const float* xw_g = ws + WS_XW;

  // one-time staging
  for (int i = tid; i < 4096; i += 256)
    *(float4*)&lw_s[i * 4] = *(const float4*)&lin_w[i * 4];
  if (tid < R) { linb_s[tid] = lin_b[tid]; lin2_s[tid] = lin2_w[tid]; }
  if (tid < ROWS) scale_s[tid] = ws[WS_ATT + row0 + tid];
  if (tid < ROWS * D_DYN) {
    int r = tid / 5, j = tid % 5;
    xw_s[r * 8 + j] = xw_g[((row0 + r) * T_STEPS + 0) * 5 + j];
  }
  __syncthreads();

  const int c0 = tid * 2;                    // 2 consecutive z-columns per thread
  const float lin2b = lin2_b[0];

  for (int t = 0; t < T_STEPS; t++) {
    // issue next-step xw load early (latency hides under Phase A)
    float xnext = 0.f;
    if (tid < ROWS * D_DYN && t + 1 < T_STEPS) {
      int r = tid / 5, j = tid % 5;
      xnext = xw_g[((row0 + r) * T_STEPS + (t + 1)) * 5 + j];
    }

    // ---- Phase A: z = xw@Wih + h@Whh + b ----
    float2 acc[ROWS];
    {
      float2 bv = *(const float2*)&b_lstm[c0];
#pragma unroll
      for (int r = 0; r < ROWS; r++) acc[r] = bv;
#pragma unroll
      for (int j = 0; j < D_DYN; j++) {
        float2 w = *(const float2*)&Wih[j * Z4 + c0];
#pragma unroll
        for (int r = 0; r < ROWS; r++) {
          float x = xw_s[r * 8 + j];
          acc[r].x = fmaf(x, w.x, acc[r].x);
          acc[r].y = fmaf(x, w.y, acc[r].y);
        }
      }
      if (t > 0) {
        float2 wc0, wc1, wc2, wc3, wc4, wc5, wc6, wc7;
        float2 wn0, wn1, wn2, wn3, wn4, wn5, wn6, wn7;
        wc0 = *(const float2*)&Whh[0 * Z4 + c0]; wc1 = *(const float2*)&Whh[1 * Z4 + c0];
        wc2 = *(const float2*)&Whh[2 * Z4 + c0]; wc3 = *(const float2*)&Whh[3 * Z4 + c0];
        wc4 = *(const float2*)&Whh[4 * Z4 + c0]; wc5 = *(const float2*)&Whh[5 * Z4 + c0];
        wc6 = *(const float2*)&Whh[6 * Z4 + c0]; wc7 = *(const float2*)&Whh[7 * Z4 + c0];
        for (int k0 = 0; k0 < R; k0 += 8) {
          if (k0 + 8 < R) {
            const float* wp = &Whh[(k0 + 8) * Z4 + c0];
            wn0 = *(const float2*)&wp[0 * Z4]; wn1 = *(const float2*)&wp[1 * Z4];
            wn2 = *(const float2*)&wp[2 * Z4]; wn3 = *(const float2*)&wp[3 * Z4];
            wn4 = *(const float2*)&wp[4 * Z4]; wn5 = *(const float2*)&wp[5 * Z4];
            wn6 = *(const float2*)&wp[6 * Z4]; wn7 = *(const float2*)&wp[7 * Z4];
          }
#pragma unroll
          for (int r = 0; r < ROWS; r++) {
            const float4 ha = *(const float4*)&h_s[r * R + k0];
            const float4 hb = *(const float4*)&h_s[r * R + k0 + 4];
            float2 a = acc[r];
            a.x = fmaf(ha.x, wc0.x, a.x); a.y = fmaf(ha.x, wc0.y, a.y);
            a.x = fmaf(ha.y, wc1.x, a.x); a.y = fmaf(ha.y, wc1.y, a.y);
            a.x = fmaf(ha.z, wc2.x, a.x); a.y = fmaf(ha.z, wc2.y, a.y);
            a.x = fmaf(ha.w, wc3.x, a.x); a.y = fmaf(ha.w, wc3.y, a.y);
            a.x = fmaf(hb.x, wc4.x, a.x); a.y = fmaf(hb.x, wc4.y, a.y);
            a.x = fmaf(hb.y, wc5.x, a.x); a.y = fmaf(hb.y, wc5.y, a.y);
            a.x = fmaf(hb.z, wc6.x, a.x); a.y = fmaf(hb.z, wc6.y, a.y);
            a.x = fmaf(hb.w, wc7.x, a.x); a.y = fmaf(hb.w, wc7.y, a.y);
            acc[r] = a;
          }
          wc0 = wn0; wc1 = wn1; wc2 = wn2; wc3 = wn3;
          wc4 = wn4; wc5 = wn5; wc6 = wn6; wc7 = wn7;
        }
      }
#pragma unroll
      for (int r = 0; r < ROWS; r++) *(float2*)&z_s[r * Z4 + c0] = acc[r];
    }
    __syncthreads();   // S1: z visible

    // ---- Phase B: gate update ----
#pragma unroll
    for (int q = 0; q < 6; q++) {
      int u = q * 256 + tid;
      int r = u >> 7, hd = u & 127;
      float zi = z_s[r * Z4 + hd];
      float zf = z_s[r * Z4 + R + hd];
      float zg = z_s[r * Z4 + 2 * R + hd];
      float zo = z_s[r * Z4 + 3 * R + hd];
      float ig = sigf(zi), fg = sigf(zf), og = sigf(zo), gg = tanhf(zg);
      float cold = (t > 0) ? c_s[r * R + hd] : 0.0f;
      float cn = fmaf(fg, cold, ig * gg);
      float hn = og * tanhf(cn);
      c_s[r * R + hd] = cn;
      h_s[r * R + hd] = hn;
      if (t == T_STEPS - 1) {
        out[OUT_HT + (row0 + r) * R + hd] = hn;
        out[OUT_CT + (row0 + r) * R + hd] = cn;
      }
    }
    if (tid < ROWS * D_DYN && t + 1 < T_STEPS) {
      int r = tid / 5, j = tid % 5;
      xw_s[r * 8 + j] = xnext;          // safe: Phase A reads ended at S1
    }
    __syncthreads();   // S2: new h visible

    // ---- Phase C: head g = h@lin_w, val = leaky(scale*g + lin_b), p = val*lin2 ----
    {
      int rg = tid >> 6;                 // wave id 0..3 -> rows rg*3..rg*3+2
      int cg = tid & 63;
      int ca = cg, cb = cg + 64;         // stride-1 cols per lane: conflict-free LDS
      float g0a = 0.f, g0b = 0.f, g1a = 0.f, g1b = 0.f, g2a = 0.f, g2b = 0.f;
      const int rb0 = (rg * 3 + 0) * R, rb1 = rb0 + R, rb2 = rb1 + R;
      for (int k0 = 0; k0 < R; k0 += 4) {
        float4 h0 = *(const float4*)&h_s[rb0 + k0];
        float4 h1 = *(const float4*)&h_s[rb1 + k0];
        float4 h2 = *(const float4*)&h_s[rb2 + k0];
        float wa, wb;
        wa = lw_s[(k0 + 0) * R + ca]; wb = lw_s[(k0 + 0) * R + cb];
        g0a = fmaf(h0.x, wa, g0a); g0b = fmaf(h0.x, wb, g0b);
        g1a = fmaf(h1.x, wa, g1a); g1b = fmaf(h1.x, wb, g1b);
        g2a = fmaf(h2.x, wa, g2a); g2b = fmaf(h2.x, wb, g2b);
        wa = lw_s[(k0 + 1) * R + ca]; wb = lw_s[(k0 + 1) * R + cb];
        g0a = fmaf(h0.y, wa, g0a); g0b = fmaf(h0.y, wb, g0b);
        g1a = fmaf(h1.y, wa, g1a); g1b = fmaf(h1.y, wb, g1b);
        g2a = fmaf(h2.y, wa, g2a); g2b = fmaf(h2.y, wb, g2b);
        wa = lw_s[(k0 + 2) * R + ca]; wb = lw_s[(k0 + 2) * R + cb];
        g0a = fmaf(h0.z, wa, g0a); g0b = fmaf(h0.z, wb, g0b);
        g1a = fmaf(h1.z, wa, g1a); g1b = fmaf(h1.z, wb, g1b);
        g2a = fmaf(h2.z, wa, g2a); g2b = fmaf(h2.z, wb, g2b);
        wa = lw_s[(k0 + 3) * R + ca]; wb = lw_s[(k0 + 3) * R + cb];
        g0a = fmaf(h0.w, wa, g0a); g0b = fmaf(h0.w, wb, g0b);
        g1a = fmaf(h1.w, wa, g1a); g1b = fmaf(h1.w, wb, g1b);
        g2a = fmaf(h2.w, wa, g2a); g2b = fmaf(h2.w, wb, g2b);
      }
      float sc0 = scale_s[rg * 3 + 0], sc1 = scale_s[rg * 3 + 1], sc2 = scale_s[rg * 3 + 2];
      float lba = linb_s[ca], lbb = linb_s[cb];
      float l2a = lin2_s[ca], l2b = lin2_s[cb];
      float p0 = leakyf(fmaf(sc0, g0a, lba)) * l2a + leakyf(fmaf(sc0, g0b, lbb)) * l2b;
      float p1 = leakyf(fmaf(sc1, g1a, lba)) * l2a + leakyf(fmaf(sc1, g1b, lbb)) * l2b;
      float p2 = leakyf(fmaf(sc2, g2a, lba)) * l2a + leakyf(fmaf(sc2, g2b, lbb)) * l2b;
      z_s[(rg * 3 + 0) * 64 + cg] = p0;
      z_s[(rg * 3 + 1) * 64 + cg] = p1;
      z_s[(rg * 3 + 2) * 64 + cg] = p2;
    }
    __syncthreads();   // S3
    if (tid < 96) {
      int r = tid >> 3, p = tid & 7;
      float s = 0.f;
#pragma unroll
      for (int m = 0; m < 8; m++) s += z_s[r * 64 + p * 8 + m];
      z_s[1024 + r * 8 + p] = s;
    }
    __syncthreads();   // S4
    if (tid < ROWS) {
      float s = lin2b;
#pragma unroll
      for (int p = 0; p < 8; p++) s += z_s[1024 + tid * 8 + p];
      out[OUT_Y + (row0 + tid) * T_STEPS + t] = s;
    }
    __syncthreads();   // S5: guard z_s reuse by next iteration's Phase A
  }
}

// ---------------------------------------------------------------------------
extern "C" void kernel_launch(void* const* d_in, const int* in_sizes, int n_in,
                              void* d_out, int out_size, void* d_ws, size_t ws_size,
                              hipStream_t stream) {
  const float* dynamic = (const float*)d_in[0];
  const float* pop     = (const float*)d_in[1];
  const float* demo    = (const float*)d_in[2];
  const float* eco     = (const float*)d_in[3];
  const float* geo     = (const float*)d_in[4];
  const float* W_pop   = (const float*)d_in[5];
  const float* a_pop   = (const float*)d_in[6];
  const float* W_demo  = (const float*)d_in[7];
  const float* a_demo  = (const float*)d_in[8];
  const float* W_eco   = (const float*)d_in[9];
  const float* a_eco   = (const float*)d_in[10];
  const float* W_geo   = (const float*)d_in[11];
  const float* a_geo   = (const float*)d_in[12];
  const float* cw_w1   = (const float*)d_in[13];
  const float* cw_b1   = (const float*)d_in[14];
  const float* cw_w2   = (const float*)d_in[15];
  const float* cw_b2   = (const float*)d_in[16];
  const float* hw_w1   = (const float*)d_in[17];
  const float* hw_b1   = (const float*)d_in[18];
  const float* hw_w2   = (const float*)d_in[19];
  const float* hw_b2   = (const float*)d_in[20];
  const float* Wih     = (const float*)d_in[21];
  const float* Whh     = (const float*)d_in[22];
  const float* b_lstm  = (const float*)d_in[23];
  const float* lin_w   = (const float*)d_in[24];
  const float* lin_b   = (const float*)d_in[25];
  const float* lin2_w  = (const float*)d_in[26];
  const float* lin2_b  = (const float*)d_in[27];

  float* out = (float*)d_out;
  float* ws  = (float*)d_ws;

  scores_kernel<<<12, 256, 0, stream>>>(pop, demo, eco, W_pop, a_pop,
                                        W_demo, a_demo, W_eco, a_eco,
                                        W_geo, a_geo, ws);
  weights_kernel<<<750, 256, 0, stream>>>(dynamic, cw_w1, cw_b1, cw_w2, cw_b2,
                                          hw_w1, hw_b1, hw_w2, hw_b2, out, ws);
  dist_kernel<<<N_NODES, 256, 0, stream>>>(geo, out, ws);

  size_t lds_bytes = (size_t)(16384 + ROWS * R * 2 + ROWS * Z4 + ROWS * 8 + 16 + R + R) * sizeof(float);
  lstm_kernel<<<NBLK, 256, lds_bytes, stream>>>(Wih, Whh, b_lstm,
                                                lin_w, lin_b, lin2_w, lin2_b,
                                                ws, out);
}

// Round 2
// 754.434 us; speedup vs baseline: 1.6048x; 1.6048x over previous
//
#include <hip/hip_runtime.h>
#include <hip/hip_bf16.h>

#define N_NODES 3000
#define T_STEPS 64
#define D_DYN   5
#define POP     16
#define DEMO    32
#define ECO     16
#define R       128
#define Z4      512
#define SLOPE   0.01f

#define NBLK    250      // 12 real rows per block, 16-row MFMA tile

// ---- workspace layout (floats) ----
#define WS_S1P 0
#define WS_S1D 3000
#define WS_S1E 6000
#define WS_S2P 9000
#define WS_S2D 12000
#define WS_S2E 15000
#define WS_GV  18000
#define WS_ATT 18432      // 3000
#define WS_XW  21504      // N*T*5 = 960000
#define WS_PACK_F 981504  // packed MFMA fragments start here (as ushort)
// pack region (ushort offsets within wsu):
//   [0,65536)        Whh hi frags
//   [65536,131072)   Whh lo frags
//   [131072,147456)  lin_w hi frags
//   [147456,163840)  lin_w lo frags

// ---- output layout (floats) ----
#define OUT_Y    0
#define OUT_DIST 192000
#define OUT_TW   9192000
#define OUT_HT   10152000
#define OUT_CT   10536000

typedef __bf16 bf16x8 __attribute__((ext_vector_type(8)));
typedef float  f32x4  __attribute__((ext_vector_type(4)));

__device__ __forceinline__ float sigf(float x)   { return 1.0f / (1.0f + __expf(-x)); }
__device__ __forceinline__ float leakyf(float x) { return x >= 0.0f ? x : SLOPE * x; }
// overflow-safe tanh: 1 - 2/(e^{2x}+1)  (x=+inf -> 1, x=-inf -> -1, no NaN)
__device__ __forceinline__ float tanhfast(float x) {
  float e2 = __expf(2.0f * x);
  return 1.0f - 2.0f / (e2 + 1.0f);
}

// ---------------------------------------------------------------------------
// Kernel 0: pack Whh and lin_w into MFMA B-fragment layout (bf16 hi/lo)
// B-frag for 16x16x32: lane l, elem i -> B[k=(kc*32+(l>>4)*8+i)][n=ct*16+(l&15)]
// ---------------------------------------------------------------------------
__global__ __launch_bounds__(256) void pack_kernel(
    const float* __restrict__ Whh, const float* __restrict__ lin_w,
    unsigned short* __restrict__ wsu)
{
  int idx = blockIdx.x * 256 + threadIdx.x;   // grid 320*256 = 81920 exact
  if (idx < 65536) {
    int i = idx & 7, lane = (idx >> 3) & 63, kc = (idx >> 9) & 3, ct = idx >> 11;
    int k = kc * 32 + ((lane >> 4) << 3) + i;
    int n = ct * 16 + (lane & 15);
    float v = Whh[k * Z4 + n];
    __bf16 hi = (__bf16)v;
    __bf16 lo = (__bf16)(v - (float)hi);
    wsu[idx]         = __builtin_bit_cast(unsigned short, hi);
    wsu[65536 + idx] = __builtin_bit_cast(unsigned short, lo);
  } else {
    int q = idx - 65536;                       // < 16384
    int i = q & 7, lane = (q >> 3) & 63, kc = (q >> 9) & 3, ct = q >> 11;
    int k = kc * 32 + ((lane >> 4) << 3) + i;
    int n = ct * 16 + (lane & 15);
    float v = lin_w[k * R + n];
    __bf16 hi = (__bf16)v;
    __bf16 lo = (__bf16)(v - (float)hi);
    wsu[131072 + q] = __builtin_bit_cast(unsigned short, hi);
    wsu[147456 + q] = __builtin_bit_cast(unsigned short, lo);
  }
}

// ---------------------------------------------------------------------------
// Kernel 1: per-node pair-score vectors (unchanged from r1)
// ---------------------------------------------------------------------------
__global__ __launch_bounds__(256) void scores_kernel(
    const float* __restrict__ pop,  const float* __restrict__ demo,
    const float* __restrict__ eco,
    const float* __restrict__ W_pop,  const float* __restrict__ a_pop,
    const float* __restrict__ W_demo, const float* __restrict__ a_demo,
    const float* __restrict__ W_eco,  const float* __restrict__ a_eco,
    const float* __restrict__ W_geo,  const float* __restrict__ a_geo,
    float* __restrict__ ws)
{
  int i = blockIdx.x * blockDim.x + threadIdx.x;
  if (i == 0) {
    float a0 = a_geo[0], a1 = a_geo[1];
    ws[WS_GV + 0] = W_geo[0] * a0 + W_geo[1] * a1;
    ws[WS_GV + 1] = W_geo[2] * a0 + W_geo[3] * a1;
  }
  if (i >= N_NODES) return;
  {
    float x[POP];
#pragma unroll
    for (int k = 0; k < POP; k++) x[k] = pop[i * POP + k];
    float s1 = 0.f, s2 = 0.f;
#pragma unroll
    for (int r = 0; r < POP; r++) {
      float h = 0.f;
#pragma unroll
      for (int k = 0; k < POP; k++) h = fmaf(x[k], W_pop[k * POP + r], h);
      s1 = fmaf(h, a_pop[r], s1);
      s2 = fmaf(h, a_pop[POP + r], s2);
    }
    ws[WS_S1P + i] = s1; ws[WS_S2P + i] = s2;
  }
  {
    float x[DEMO];
#pragma unroll
    for (int k = 0; k < DEMO; k++) x[k] = demo[i * DEMO + k];
    float s1 = 0.f, s2 = 0.f;
#pragma unroll 4
    for (int r = 0; r < DEMO; r++) {
      float h = 0.f;
#pragma unroll
      for (int k = 0; k < DEMO; k++) h = fmaf(x[k], W_demo[k * DEMO + r], h);
      s1 = fmaf(h, a_demo[r], s1);
      s2 = fmaf(h, a_demo[DEMO + r], s2);
    }
    ws[WS_S1D + i] = s1; ws[WS_S2D + i] = s2;
  }
  {
    float x[ECO];
#pragma unroll
    for (int k = 0; k < ECO; k++) x[k] = eco[i * ECO + k];
    float s1 = 0.f, s2 = 0.f;
#pragma unroll
    for (int r = 0; r < ECO; r++) {
      float h = 0.f;
#pragma unroll
      for (int k = 0; k < ECO; k++) h = fmaf(x[k], W_eco[k * ECO + r], h);
      s1 = fmaf(h, a_eco[r], s1);
      s2 = fmaf(h, a_eco[ECO + r], s2);
    }
    ws[WS_S1E + i] = s1; ws[WS_S2E + i] = s2;
  }
}

// ---------------------------------------------------------------------------
// Kernel 2: gate MLPs (unchanged from r1)
// ---------------------------------------------------------------------------
__global__ __launch_bounds__(256) void weights_kernel(
    const float* __restrict__ dyn,
    const float* __restrict__ cw_w1, const float* __restrict__ cw_b1,
    const float* __restrict__ cw_w2, const float* __restrict__ cw_b2,
    const float* __restrict__ hw_w1, const float* __restrict__ hw_b1,
    const float* __restrict__ hw_w2, const float* __restrict__ hw_b2,
    float* __restrict__ out, float* __restrict__ ws)
{
  __shared__ float s_cw1[R], s_cb1[R], s_cw2[R], s_hb1[R];
  __shared__ float s_hw1[4 * R], s_hw2[R * 4];
  int tid = threadIdx.x;
  if (tid < R) {
    s_cw1[tid] = cw_w1[tid]; s_cb1[tid] = cw_b1[tid];
    s_cw2[tid] = cw_w2[tid]; s_hb1[tid] = hw_b1[tid];
  }
  for (int i = tid; i < 4 * R; i += 256) { s_hw1[i] = hw_w1[i]; s_hw2[i] = hw_w2[i]; }
  __syncthreads();

  int idx = blockIdx.x * 256 + tid;
  float x0 = dyn[idx * 5 + 0], x1 = dyn[idx * 5 + 1], x2 = dyn[idx * 5 + 2];
  float x3 = dyn[idx * 5 + 3], x4 = dyn[idx * 5 + 4];

  float acc = 0.f, o0 = 0.f, o1 = 0.f, o2 = 0.f, o3 = 0.f;
#pragma unroll 8
  for (int r = 0; r < R; r++) {
    float u = leakyf(fmaf(x0, s_cw1[r], s_cb1[r]));
    acc = fmaf(u, s_cw2[r], acc);
    float v = s_hb1[r];
    v = fmaf(x1, s_hw1[r], v);
    v = fmaf(x2, s_hw1[R + r], v);
    v = fmaf(x3, s_hw1[2 * R + r], v);
    v = fmaf(x4, s_hw1[3 * R + r], v);
    v = leakyf(v);
    o0 = fmaf(v, s_hw2[r * 4 + 0], o0);
    o1 = fmaf(v, s_hw2[r * 4 + 1], o1);
    o2 = fmaf(v, s_hw2[r * 4 + 2], o2);
    o3 = fmaf(v, s_hw2[r * 4 + 3], o3);
  }
  float tw0 = sigf(acc + cw_b2[0]);
  float tw1 = sigf(o0 + hw_b2[0]);
  float tw2 = sigf(o1 + hw_b2[1]);
  float tw3 = sigf(o2 + hw_b2[2]);
  float tw4 = sigf(o3 + hw_b2[3]);

  out[OUT_TW + idx * 5 + 0] = tw0;
  out[OUT_TW + idx * 5 + 1] = tw1;
  out[OUT_TW + idx * 5 + 2] = tw2;
  out[OUT_TW + idx * 5 + 3] = tw3;
  out[OUT_TW + idx * 5 + 4] = tw4;

  ws[WS_XW + idx * 5 + 0] = tw0 * x0;
  ws[WS_XW + idx * 5 + 1] = tw1 * x1;
  ws[WS_XW + idx * 5 + 2] = tw2 * x2;
  ws[WS_XW + idx * 5 + 3] = tw3 * x3;
  ws[WS_XW + idx * 5 + 4] = tw4 * x4;
}

// ---------------------------------------------------------------------------
// Kernel 3: dist rows + att_scale. vals[] now statically indexed (rule #20:
// runtime-indexed arrays go to scratch; 12 fixed trips keep it in VGPRs).
// ---------------------------------------------------------------------------
__global__ __launch_bounds__(256) void dist_kernel(
    const float* __restrict__ geo, float* __restrict__ out, float* __restrict__ ws)
{
  int i = blockIdx.x;
  int tid = threadIdx.x;
  __shared__ float sm[20];

  float s1p = ws[WS_S1P + i], s1d = ws[WS_S1D + i], s1e = ws[WS_S1E + i];
  float gv0 = ws[WS_GV + 0], gv1 = ws[WS_GV + 1];

  float vals[12];
  float vmax = -3.0e38f;
#pragma unroll
  for (int u = 0; u < 12; u++) {
    int j = tid + u * 256;
    float v = -3.0e38f;
    if (j < N_NODES) {
      float2 g = *(const float2*)&geo[((size_t)i * N_NODES + j) * 2];
      v = sigf(s1p + ws[WS_S2P + j]) + sigf(s1d + ws[WS_S2D + j]) +
          sigf(s1e + ws[WS_S2E + j]) + sigf(fmaf(g.x, gv0, g.y * gv1));
    }
    vals[u] = v;
    vmax = fmaxf(vmax, v);
  }
  int wid = tid >> 6, lane = tid & 63;
  for (int off = 32; off; off >>= 1) vmax = fmaxf(vmax, __shfl_down(vmax, off, 64));
  if (lane == 0) sm[wid] = vmax;
  __syncthreads();
  if (tid == 0) sm[8] = fmaxf(fmaxf(sm[0], sm[1]), fmaxf(sm[2], sm[3]));
  __syncthreads();
  vmax = sm[8];

  float lsum = 0.f;
#pragma unroll
  for (int u = 0; u < 12; u++) {
    int j = tid + u * 256;
    float e = (j < N_NODES) ? __expf(vals[u] - vmax) : 0.f;
    vals[u] = e;
    lsum += e;
  }
  for (int off = 32; off; off >>= 1) lsum += __shfl_down(lsum, off, 64);
  if (lane == 0) sm[4 + wid] = lsum;
  __syncthreads();
  if (tid == 0) sm[9] = sm[4] + sm[5] + sm[6] + sm[7];
  __syncthreads();
  float inv = 1.0f / sm[9];

  float rs = 0.f;
#pragma unroll
  for (int u = 0; u < 12; u++) {
    int j = tid + u * 256;
    if (j < N_NODES) {
      float wv = vals[u] * inv;
      out[OUT_DIST + (size_t)i * N_NODES + j] = wv;
      rs += wv;
    }
  }
  for (int off = 32; off; off >>= 1) rs += __shfl_down(rs, off, 64);
  if (lane == 0) sm[10 + wid] = rs;
  __syncthreads();
  if (tid == 0) ws[WS_ATT + i] = 1.0f + (sm[10] + sm[11] + sm[12] + sm[13]);
}

// ---------------------------------------------------------------------------
// Kernel 4: persistent MFMA LSTM (bf16x3 split precision) + fused head.
// 250 blocks x 512 thr (8 waves, 2/SIMD). 12 real rows/block, 16-row tile.
// Whh B-fragments resident in 128 VGPRs for all 64 steps (zero weight traffic).
// h stored per step as swizzled bf16 hi/lo in LDS -> A-fragments.
// ---------------------------------------------------------------------------
// LDS byte layout (static, 42304 B):
#define ZSTR     516                    // floats per z row (bank-stagger)
#define Z_BYTES  (16 * ZSTR * 4)        // 33024
#define HHI_OFF  33024                  // [16][128] bf16, XOR-swizzled
#define HLO_OFF  37120
#define XW_OFF   41216                  // [16][8] f32
#define SC_OFF   41728                  // 16 f32
#define YR_OFF   41792                  // [16][8] f32
#define LDS_TOT  42304

__global__ __launch_bounds__(512, 2) void lstm_kernel(
    const float* __restrict__ Wih, const float* __restrict__ b_lstm,
    const float* __restrict__ lin_b, const float* __restrict__ lin2_w,
    const float* __restrict__ lin2_b,
    const unsigned short* __restrict__ wsu,
    const float* __restrict__ ws,
    float* __restrict__ out)
{
  __shared__ float smf[LDS_TOT / 4];
  char* smraw = (char*)smf;
  float* z_lds = smf;

  int tid = threadIdx.x;
  int w = tid >> 6, lane = tid & 63;
  int lg = lane >> 4, lc = lane & 15;
  int row0 = blockIdx.x * 12;

  // ---- persistent Whh B-fragments (hi/lo), 128 VGPRs ----
  bf16x8 bwh[4][4], bwl[4][4];
#pragma unroll
  for (int tt = 0; tt < 4; tt++)
#pragma unroll
    for (int kc = 0; kc < 4; kc++) {
      int off = ((w * 4 + tt) * 4 + kc) * 512 + lane * 8;
      bwh[tt][kc] = *(const bf16x8*)(wsu + off);
      bwl[tt][kc] = *(const bf16x8*)(wsu + 65536 + off);
    }
  // per-lane constants
  float wih_r[4][5], bz[4];
#pragma unroll
  for (int tt = 0; tt < 4; tt++) {
    int cz = (w * 4 + tt) * 16 + lc;
    bz[tt] = b_lstm[cz];
#pragma unroll
    for (int d = 0; d < 5; d++) wih_r[tt][d] = Wih[d * Z4 + cz];
  }
  int hcol = w * 16 + lc;
  float lbv = lin_b[hcol], l2v = lin2_w[hcol];
  float l2b = lin2_b[0];

  // zero h-pack (8 KB), stage scale + xw(t=0)
  {
    unsigned int* hp = (unsigned int*)(smraw + HHI_OFF);
    for (int p = tid; p < 2048; p += 512) hp[p] = 0u;
  }
  if (tid < 16) {
    int rg = row0 + tid; if (rg > 2999) rg = 2999;
    *(float*)(smraw + SC_OFF + tid * 4) = ws[WS_ATT + rg];
  }
  if (tid < 80) {
    int r = tid / 5, d = tid % 5;
    int rg = row0 + r; if (rg > 2999) rg = 2999;
    *(float*)(smraw + XW_OFF + (r * 8 + d) * 4) =
        ws[WS_XW + ((size_t)rg * T_STEPS + 0) * 5 + d];
  }
  int hd = tid & 127, rgrp = tid >> 7;
  float cst[4] = {0.f, 0.f, 0.f, 0.f};
  __syncthreads();

  for (int t = 0; t < T_STEPS; t++) {
    // prefetch next step's xw into a register (written to LDS after S1)
    float xnext = 0.f;
    int pr = tid / 5, pd = tid - pr * 5;
    if (tid < 80) {
      int rg = row0 + pr; if (rg > 2999) rg = 2999;
      int tn = (t + 1 < T_STEPS) ? t + 1 : T_STEPS - 1;
      xnext = ws[WS_XW + ((size_t)rg * T_STEPS + tn) * 5 + pd];
    }

    // ---- Phase A: z = xw@Wih + b + h@Whh (MFMA bf16x3) ----
    f32x4 acc[4];
#pragma unroll
    for (int j = 0; j < 4; j++) {
      const float* xp = (const float*)(smraw + XW_OFF) + (lg * 4 + j) * 8;
      float x0 = xp[0], x1 = xp[1], x2 = xp[2], x3 = xp[3], x4 = xp[4];
#pragma unroll
      for (int tt = 0; tt < 4; tt++) {
        float a = bz[tt];
        a = fmaf(x0, wih_r[tt][0], a);
        a = fmaf(x1, wih_r[tt][1], a);
        a = fmaf(x2, wih_r[tt][2], a);
        a = fmaf(x3, wih_r[tt][3], a);
        a = fmaf(x4, wih_r[tt][4], a);
        acc[tt][j] = a;
      }
    }
    {
      bf16x8 ah[4], al[4];
#pragma unroll
      for (int kc = 0; kc < 4; kc++) {
        int cb = (kc * 64 + lg * 16) ^ ((lc & 7) << 4);
        ah[kc] = *(bf16x8*)(smraw + HHI_OFF + lc * 256 + cb);
        al[kc] = *(bf16x8*)(smraw + HLO_OFF + lc * 256 + cb);
      }
#pragma unroll
      for (int kc = 0; kc < 4; kc++) {
#pragma unroll
        for (int tt = 0; tt < 4; tt++)
          acc[tt] = __builtin_amdgcn_mfma_f32_16x16x32_bf16(ah[kc], bwh[tt][kc], acc[tt], 0, 0, 0);
#pragma unroll
        for (int tt = 0; tt < 4; tt++)
          acc[tt] = __builtin_amdgcn_mfma_f32_16x16x32_bf16(ah[kc], bwl[tt][kc], acc[tt], 0, 0, 0);
#pragma unroll
        for (int tt = 0; tt < 4; tt++)
          acc[tt] = __builtin_amdgcn_mfma_f32_16x16x32_bf16(al[kc], bwh[tt][kc], acc[tt], 0, 0, 0);
      }
    }
#pragma unroll
    for (int tt = 0; tt < 4; tt++) {
      float* zp = z_lds + (lg * 4) * ZSTR + (w * 4 + tt) * 16 + lc;
#pragma unroll
      for (int j = 0; j < 4; j++) zp[j * ZSTR] = acc[tt][j];
    }
    __syncthreads();  // S1: z visible

    // ---- Phase B: gates (VALU), c-state in regs; prefetch lin frags (L2) ----
    bf16x8 lh[4], ll[4];
#pragma unroll
    for (int kc = 0; kc < 4; kc++) {
      int goff = 131072 + (w * 4 + kc) * 512 + lane * 8;
      lh[kc] = *(const bf16x8*)(wsu + goff);
      ll[kc] = *(const bf16x8*)(wsu + goff + 16384);
    }
    {
      float hval[4];
#pragma unroll
      for (int q = 0; q < 4; q++) {
        int r = rgrp * 4 + q;
        const float* zp = z_lds + r * ZSTR + hd;
        float zi = zp[0], zf = zp[128], zg = zp[256], zo = zp[384];
        float ig = sigf(zi), fg = sigf(zf), og = sigf(zo);
        float gg = tanhfast(zg);
        float cn = fmaf(fg, cst[q], ig * gg);
        float hn = og * tanhfast(cn);
        cst[q] = cn;
        hval[q] = hn;
        __bf16 hh = (__bf16)hn;
        __bf16 hl = (__bf16)(hn - (float)hh);
        int cbyte = (hd * 2) ^ ((r & 7) << 4);
        *(unsigned short*)(smraw + HHI_OFF + r * 256 + cbyte) = __builtin_bit_cast(unsigned short, hh);
        *(unsigned short*)(smraw + HLO_OFF + r * 256 + cbyte) = __builtin_bit_cast(unsigned short, hl);
      }
      if (t == T_STEPS - 1) {
#pragma unroll
        for (int q = 0; q < 4; q++) {
          int r = rgrp * 4 + q;
          if (r < 12) {
            out[OUT_HT + (size_t)(row0 + r) * R + hd] = hval[q];
            out[OUT_CT + (size_t)(row0 + r) * R + hd] = cst[q];
          }
        }
      }
      if (tid < 80)
        *(float*)(smraw + XW_OFF + (pr * 8 + pd) * 4) = xnext;
    }
    __syncthreads();  // S2: new h visible

    // ---- Phase C: head G = h @ lin_w (MFMA bf16x3), fused epilogue ----
    {
      f32x4 g = {0.f, 0.f, 0.f, 0.f};
#pragma unroll
      for (int kc = 0; kc < 4; kc++) {
        int cb = (kc * 64 + lg * 16) ^ ((lc & 7) << 4);
        bf16x8 ah = *(bf16x8*)(smraw + HHI_OFF + lc * 256 + cb);
        bf16x8 al = *(bf16x8*)(smraw + HLO_OFF + lc * 256 + cb);
        g = __builtin_amdgcn_mfma_f32_16x16x32_bf16(ah, lh[kc], g, 0, 0, 0);
        g = __builtin_amdgcn_mfma_f32_16x16x32_bf16(ah, ll[kc], g, 0, 0, 0);
        g = __builtin_amdgcn_mfma_f32_16x16x32_bf16(al, lh[kc], g, 0, 0, 0);
      }
#pragma unroll
      for (int j = 0; j < 4; j++) {
        int rr = lg * 4 + j;
        float sc = *(float*)(smraw + SC_OFF + rr * 4);
        float val = leakyf(fmaf(sc, g[j], lbv)) * l2v;
        z_lds[rr * ZSTR + hcol] = val;   // reuse z_lds as y_part[16][128]
      }
    }
    __syncthreads();  // S3
    if (tid < 128) {
      int r = tid >> 3, p = tid & 7;
      float s = 0.f;
#pragma unroll
      for (int m = 0; m < 16; m++) s += z_lds[r * ZSTR + p * 16 + m];
      *(float*)(smraw + YR_OFF + (r * 8 + p) * 4) = s;
    }
    __syncthreads();  // S4
    if (tid < 12) {
      float s = l2b;
#pragma unroll
      for (int p = 0; p < 8; p++) s += *(float*)(smraw + YR_OFF + (tid * 8 + p) * 4);
      out[OUT_Y + (size_t)(row0 + tid) * T_STEPS + t] = s;
    }
    // no S5 needed: any thread entering next Phase A has passed S4, and all
    // y_part readers arrived at S4 only after their reads completed.
  }
}

// ---------------------------------------------------------------------------
extern "C" void kernel_launch(void* const* d_in, const int* in_sizes, int n_in,
                              void* d_out, int out_size, void* d_ws, size_t ws_size,
                              hipStream_t stream) {
  const float* dynamic = (const float*)d_in[0];
  const float* pop     = (const float*)d_in[1];
  const float* demo    = (const float*)d_in[2];
  const float* eco     = (const float*)d_in[3];
  const float* geo     = (const float*)d_in[4];
  const float* W_pop   = (const float*)d_in[5];
  const float* a_pop   = (const float*)d_in[6];
  const float* W_demo  = (const float*)d_in[7];
  const float* a_demo  = (const float*)d_in[8];
  const float* W_eco   = (const float*)d_in[9];
  const float* a_eco   = (const float*)d_in[10];
  const float* W_geo   = (const float*)d_in[11];
  const float* a_geo   = (const float*)d_in[12];
  const float* cw_w1   = (const float*)d_in[13];
  const float* cw_b1   = (const float*)d_in[14];
  const float* cw_w2   = (const float*)d_in[15];
  const float* cw_b2   = (const float*)d_in[16];
  const float* hw_w1   = (const float*)d_in[17];
  const float* hw_b1   = (const float*)d_in[18];
  const float* hw_w2   = (const float*)d_in[19];
  const float* hw_b2   = (const float*)d_in[20];
  const float* Wih     = (const float*)d_in[21];
  const float* Whh     = (const float*)d_in[22];
  const float* b_lstm  = (const float*)d_in[23];
  const float* lin_w   = (const float*)d_in[24];
  const float* lin_b   = (const float*)d_in[25];
  const float* lin2_w  = (const float*)d_in[26];
  const float* lin2_b  = (const float*)d_in[27];

  float* out = (float*)d_out;
  float* ws  = (float*)d_ws;
  unsigned short* wsu = (unsigned short*)(ws + WS_PACK_F);

  pack_kernel<<<320, 256, 0, stream>>>(Whh, lin_w, wsu);
  scores_kernel<<<12, 256, 0, stream>>>(pop, demo, eco, W_pop, a_pop,
                                        W_demo, a_demo, W_eco, a_eco,
                                        W_geo, a_geo, ws);
  weights_kernel<<<750, 256, 0, stream>>>(dynamic, cw_w1, cw_b1, cw_w2, cw_b2,
                                          hw_w1, hw_b1, hw_w2, hw_b2, out, ws);
  dist_kernel<<<N_NODES, 256, 0, stream>>>(geo, out, ws);
  lstm_kernel<<<NBLK, 512, 0, stream>>>(Wih, b_lstm, lin_b, lin2_w, lin2_b,
                                        wsu, ws, out);
}

// Round 3
// 407.851 us; speedup vs baseline: 2.9685x; 1.8498x over previous
//
#include <hip/hip_runtime.h>
#include <hip/hip_bf16.h>

#define N_NODES 3000
#define T_STEPS 64
#define POP     16
#define DEMO    32
#define ECO     16
#define R       128
#define SLOPE   0.01f

#define NBLK    250      // 12 real rows per block, 16-row MFMA tile

// ---- workspace layout (floats) ----
#define WS_S1P 0
#define WS_S1D 3000
#define WS_S1E 6000
#define WS_S2P 9000
#define WS_S2D 12000
#define WS_S2E 15000
#define WS_GV  18000
#define WS_ATT 18432      // 3000
#define WS_XW  21504      // N*T*5 = 960000
#define WS_PACK_F 981504  // packed MFMA fragments (as ushort)
// pack region (ushort offsets in wsu):
//   [0,65536)        Whh hi frags   (ct 0..31, kc 0..3)
//   [65536,131072)   Whh lo frags
//   [131072,147456)  lin_w hi frags (ct 0..7, kc 0..3)
//   [147456,163840)  lin_w lo frags
//   [163840,180224)  Wih+bias frags (ct 0..31, kc4): k-slots 0..4=Wih_hi,
//                    5=0, 6=b_lo, 7=b_hi (A-side supplies 1.0 at slots 6,7)

// ---- output layout (floats) ----
#define OUT_Y    0
#define OUT_DIST 192000
#define OUT_TW   9192000
#define OUT_HT   10152000
#define OUT_CT   10536000

typedef __bf16 bf16x8 __attribute__((ext_vector_type(8)));
typedef float  f32x4  __attribute__((ext_vector_type(4)));

__device__ __forceinline__ float sigf(float x)   { return 1.0f / (1.0f + __expf(-x)); }
__device__ __forceinline__ float leakyf(float x) { return x >= 0.0f ? x : SLOPE * x; }
__device__ __forceinline__ float tanhfast(float x) {
  float e2 = __expf(2.0f * x);
  return 1.0f - 2.0f / (e2 + 1.0f);
}
__device__ __forceinline__ unsigned short bfbits(float v) {
  __bf16 b = (__bf16)v;
  return __builtin_bit_cast(unsigned short, b);
}

// pin a fragment in VGPRs: asm "defines" the value -> no rematerialization
#define PIN4(x) { f32x4 _t = __builtin_bit_cast(f32x4, x); \
                  asm volatile("" : "+v"(_t)); \
                  x = __builtin_bit_cast(bf16x8, _t); }
#define PIN1(x) asm volatile("" : "+v"(x))

// ---------------------------------------------------------------------------
// Kernel 0: pack Whh, lin_w, Wih+bias into MFMA B-fragment layout (bf16 hi/lo)
// B-frag 16x16x32: lane l elem i -> B[k=kc*32+(l>>4)*8+i][n=ct*16+(l&15)]
// ---------------------------------------------------------------------------
__global__ __launch_bounds__(256) void pack_kernel(
    const float* __restrict__ Whh, const float* __restrict__ lin_w,
    const float* __restrict__ Wih, const float* __restrict__ b_lstm,
    unsigned short* __restrict__ wsu)
{
  int idx = blockIdx.x * 256 + threadIdx.x;   // 384*256 = 98304 exact
  if (idx < 65536) {
    int i = idx & 7, lane = (idx >> 3) & 63, kc = (idx >> 9) & 3, ct = idx >> 11;
    int k = kc * 32 + ((lane >> 4) << 3) + i;
    int n = ct * 16 + (lane & 15);
    float v = Whh[k * 512 + n];
    float hi = (float)(__bf16)v;
    wsu[idx]         = bfbits(v);
    wsu[65536 + idx] = bfbits(v - hi);
  } else if (idx < 81920) {
    int q = idx - 65536;                       // < 16384
    int i = q & 7, lane = (q >> 3) & 63, kc = (q >> 9) & 3, ct = q >> 11;
    int k = kc * 32 + ((lane >> 4) << 3) + i;
    int n = ct * 16 + (lane & 15);
    float v = lin_w[k * R + n];
    float hi = (float)(__bf16)v;
    wsu[131072 + q] = bfbits(v);
    wsu[147456 + q] = bfbits(v - hi);
  } else {
    int q = idx - 81920;                       // < 16384
    int i = q & 7, lane = (q >> 3) & 63, ct = q >> 9;   // ct 0..31
    int ks = ((lane >> 4) << 3) + i;           // k-slot within kc4 (0..31)
    int n = ct * 16 + (lane & 15);
    unsigned short o = 0;
    if (ks < 5) {
      o = bfbits(Wih[ks * 512 + n]);
    } else if (ks == 6) {
      float b = b_lstm[n];
      o = bfbits(b - (float)(__bf16)b);        // bias lo
    } else if (ks == 7) {
      o = bfbits(b_lstm[n]);                   // bias hi
    }
    wsu[163840 + q] = o;
  }
}

// ---------------------------------------------------------------------------
// Kernel 1: per-node pair-score vectors (unchanged)
// ---------------------------------------------------------------------------
__global__ __launch_bounds__(256) void scores_kernel(
    const float* __restrict__ pop,  const float* __restrict__ demo,
    const float* __restrict__ eco,
    const float* __restrict__ W_pop,  const float* __restrict__ a_pop,
    const float* __restrict__ W_demo, const float* __restrict__ a_demo,
    const float* __restrict__ W_eco,  const float* __restrict__ a_eco,
    const float* __restrict__ W_geo,  const float* __restrict__ a_geo,
    float* __restrict__ ws)
{
  int i = blockIdx.x * blockDim.x + threadIdx.x;
  if (i == 0) {
    float a0 = a_geo[0], a1 = a_geo[1];
    ws[WS_GV + 0] = W_geo[0] * a0 + W_geo[1] * a1;
    ws[WS_GV + 1] = W_geo[2] * a0 + W_geo[3] * a1;
  }
  if (i >= N_NODES) return;
  {
    float x[POP];
#pragma unroll
    for (int k = 0; k < POP; k++) x[k] = pop[i * POP + k];
    float s1 = 0.f, s2 = 0.f;
#pragma unroll
    for (int r = 0; r < POP; r++) {
      float h = 0.f;
#pragma unroll
      for (int k = 0; k < POP; k++) h = fmaf(x[k], W_pop[k * POP + r], h);
      s1 = fmaf(h, a_pop[r], s1);
      s2 = fmaf(h, a_pop[POP + r], s2);
    }
    ws[WS_S1P + i] = s1; ws[WS_S2P + i] = s2;
  }
  {
    float x[DEMO];
#pragma unroll
    for (int k = 0; k < DEMO; k++) x[k] = demo[i * DEMO + k];
    float s1 = 0.f, s2 = 0.f;
#pragma unroll 4
    for (int r = 0; r < DEMO; r++) {
      float h = 0.f;
#pragma unroll
      for (int k = 0; k < DEMO; k++) h = fmaf(x[k], W_demo[k * DEMO + r], h);
      s1 = fmaf(h, a_demo[r], s1);
      s2 = fmaf(h, a_demo[DEMO + r], s2);
    }
    ws[WS_S1D + i] = s1; ws[WS_S2D + i] = s2;
  }
  {
    float x[ECO];
#pragma unroll
    for (int k = 0; k < ECO; k++) x[k] = eco[i * ECO + k];
    float s1 = 0.f, s2 = 0.f;
#pragma unroll
    for (int r = 0; r < ECO; r++) {
      float h = 0.f;
#pragma unroll
      for (int k = 0; k < ECO; k++) h = fmaf(x[k], W_eco[k * ECO + r], h);
      s1 = fmaf(h, a_eco[r], s1);
      s2 = fmaf(h, a_eco[ECO + r], s2);
    }
    ws[WS_S1E + i] = s1; ws[WS_S2E + i] = s2;
  }
}

// ---------------------------------------------------------------------------
// Kernel 2: gate MLPs (unchanged)
// ---------------------------------------------------------------------------
__global__ __launch_bounds__(256) void weights_kernel(
    const float* __restrict__ dyn,
    const float* __restrict__ cw_w1, const float* __restrict__ cw_b1,
    const float* __restrict__ cw_w2, const float* __restrict__ cw_b2,
    const float* __restrict__ hw_w1, const float* __restrict__ hw_b1,
    const float* __restrict__ hw_w2, const float* __restrict__ hw_b2,
    float* __restrict__ out, float* __restrict__ ws)
{
  __shared__ float s_cw1[R], s_cb1[R], s_cw2[R], s_hb1[R];
  __shared__ float s_hw1[4 * R], s_hw2[R * 4];
  int tid = threadIdx.x;
  if (tid < R) {
    s_cw1[tid] = cw_w1[tid]; s_cb1[tid] = cw_b1[tid];
    s_cw2[tid] = cw_w2[tid]; s_hb1[tid] = hw_b1[tid];
  }
  for (int i = tid; i < 4 * R; i += 256) { s_hw1[i] = hw_w1[i]; s_hw2[i] = hw_w2[i]; }
  __syncthreads();

  int idx = blockIdx.x * 256 + tid;
  float x0 = dyn[idx * 5 + 0], x1 = dyn[idx * 5 + 1], x2 = dyn[idx * 5 + 2];
  float x3 = dyn[idx * 5 + 3], x4 = dyn[idx * 5 + 4];

  float acc = 0.f, o0 = 0.f, o1 = 0.f, o2 = 0.f, o3 = 0.f;
#pragma unroll 8
  for (int r = 0; r < R; r++) {
    float u = leakyf(fmaf(x0, s_cw1[r], s_cb1[r]));
    acc = fmaf(u, s_cw2[r], acc);
    float v = s_hb1[r];
    v = fmaf(x1, s_hw1[r], v);
    v = fmaf(x2, s_hw1[R + r], v);
    v = fmaf(x3, s_hw1[2 * R + r], v);
    v = fmaf(x4, s_hw1[3 * R + r], v);
    v = leakyf(v);
    o0 = fmaf(v, s_hw2[r * 4 + 0], o0);
    o1 = fmaf(v, s_hw2[r * 4 + 1], o1);
    o2 = fmaf(v, s_hw2[r * 4 + 2], o2);
    o3 = fmaf(v, s_hw2[r * 4 + 3], o3);
  }
  float tw0 = sigf(acc + cw_b2[0]);
  float tw1 = sigf(o0 + hw_b2[0]);
  float tw2 = sigf(o1 + hw_b2[1]);
  float tw3 = sigf(o2 + hw_b2[2]);
  float tw4 = sigf(o3 + hw_b2[3]);

  out[OUT_TW + idx * 5 + 0] = tw0;
  out[OUT_TW + idx * 5 + 1] = tw1;
  out[OUT_TW + idx * 5 + 2] = tw2;
  out[OUT_TW + idx * 5 + 3] = tw3;
  out[OUT_TW + idx * 5 + 4] = tw4;

  ws[WS_XW + idx * 5 + 0] = tw0 * x0;
  ws[WS_XW + idx * 5 + 1] = tw1 * x1;
  ws[WS_XW + idx * 5 + 2] = tw2 * x2;
  ws[WS_XW + idx * 5 + 3] = tw3 * x3;
  ws[WS_XW + idx * 5 + 4] = tw4 * x4;
}

// ---------------------------------------------------------------------------
// Kernel 3: dist rows + att_scale (unchanged, statically-indexed vals[])
// ---------------------------------------------------------------------------
__global__ __launch_bounds__(256) void dist_kernel(
    const float* __restrict__ geo, float* __restrict__ out, float* __restrict__ ws)
{
  int i = blockIdx.x;
  int tid = threadIdx.x;
  __shared__ float sm[20];

  float s1p = ws[WS_S1P + i], s1d = ws[WS_S1D + i], s1e = ws[WS_S1E + i];
  float gv0 = ws[WS_GV + 0], gv1 = ws[WS_GV + 1];

  float vals[12];
  float vmax = -3.0e38f;
#pragma unroll
  for (int u = 0; u < 12; u++) {
    int j = tid + u * 256;
    float v = -3.0e38f;
    if (j < N_NODES) {
      float2 g = *(const float2*)&geo[((size_t)i * N_NODES + j) * 2];
      v = sigf(s1p + ws[WS_S2P + j]) + sigf(s1d + ws[WS_S2D + j]) +
          sigf(s1e + ws[WS_S2E + j]) + sigf(fmaf(g.x, gv0, g.y * gv1));
    }
    vals[u] = v;
    vmax = fmaxf(vmax, v);
  }
  int wid = tid >> 6, lane = tid & 63;
  for (int off = 32; off; off >>= 1) vmax = fmaxf(vmax, __shfl_down(vmax, off, 64));
  if (lane == 0) sm[wid] = vmax;
  __syncthreads();
  if (tid == 0) sm[8] = fmaxf(fmaxf(sm[0], sm[1]), fmaxf(sm[2], sm[3]));
  __syncthreads();
  vmax = sm[8];

  float lsum = 0.f;
#pragma unroll
  for (int u = 0; u < 12; u++) {
    int j = tid + u * 256;
    float e = (j < N_NODES) ? __expf(vals[u] - vmax) : 0.f;
    vals[u] = e;
    lsum += e;
  }
  for (int off = 32; off; off >>= 1) lsum += __shfl_down(lsum, off, 64);
  if (lane == 0) sm[4 + wid] = lsum;
  __syncthreads();
  if (tid == 0) sm[9] = sm[4] + sm[5] + sm[6] + sm[7];
  __syncthreads();
  float inv = 1.0f / sm[9];

  float rs = 0.f;
#pragma unroll
  for (int u = 0; u < 12; u++) {
    int j = tid + u * 256;
    if (j < N_NODES) {
      float wv = vals[u] * inv;
      out[OUT_DIST + (size_t)i * N_NODES + j] = wv;
      rs += wv;
    }
  }
  for (int off = 32; off; off >>= 1) rs += __shfl_down(rs, off, 64);
  if (lane == 0) sm[10 + wid] = rs;
  __syncthreads();
  if (tid == 0) ws[WS_ATT + i] = 1.0f + (sm[10] + sm[11] + sm[12] + sm[13]);
}

// ---------------------------------------------------------------------------
// Kernel 4: persistent MFMA LSTM, gate-aligned tiling, z in registers.
// 250 blocks x 512 thr. Wave w, acc g covers z-cols g*128 + w*16 + lc.
// h stored in LDS in fragment-linear layout (lane l reads base + l*16):
// conflict-free ds_read_b128. xw + bias folded into MFMA as k-chunk 4.
// 2 barriers/step.
// ---------------------------------------------------------------------------
#define HB_BYTES 10240            // per buffer: hi [0,5120) + lo [5120,10240)
#define PART_OFF 20480            // partial y [16][8] f32
#define LDS_BYTES 20992

__global__ __launch_bounds__(512, 2) void lstm_kernel(
    const unsigned short* __restrict__ wsu,
    const float* __restrict__ ws,
    const float* __restrict__ lin_b, const float* __restrict__ lin2_w,
    const float* __restrict__ lin2_b,
    float* __restrict__ out)
{
  __shared__ __align__(16) char smraw[LDS_BYTES];
  int tid = threadIdx.x;
  int w = tid >> 6, lane = tid & 63;
  int lg = lane >> 4, lc = lane & 15;
  int row0 = blockIdx.x * 12;
  const float* xw_g = ws + WS_XW;

  // ---- load + pin weight fragments (176 VGPRs, resident for all 64 steps) --
  bf16x8 bwh[4][4], bwl[4][4], bih[4], lh[4], ll[4];
#pragma unroll
  for (int g = 0; g < 4; g++) {
#pragma unroll
    for (int kc = 0; kc < 4; kc++) {
      int off = (((g * 8 + w) * 4 + kc) * 512) + lane * 8;
      bwh[g][kc] = *(const bf16x8*)(wsu + off);
      bwl[g][kc] = *(const bf16x8*)(wsu + 65536 + off);
      PIN4(bwh[g][kc]); PIN4(bwl[g][kc]);
    }
    bih[g] = *(const bf16x8*)(wsu + 163840 + (g * 8 + w) * 512 + lane * 8);
    PIN4(bih[g]);
  }
#pragma unroll
  for (int kc = 0; kc < 4; kc++) {
    int off = 131072 + (w * 4 + kc) * 512 + lane * 8;
    lh[kc] = *(const bf16x8*)(wsu + off);
    ll[kc] = *(const bf16x8*)(wsu + 16384 + off);
    PIN4(lh[kc]); PIN4(ll[kc]);
  }

  int hcol = w * 16 + lc;
  float lbv = lin_b[hcol], l2v = lin2_w[hcol], l2b = lin2_b[0];
  float sc[4];
#pragma unroll
  for (int j = 0; j < 4; j++) {
    int rg = row0 + lg * 4 + j; if (rg > 2999) rg = 2999;
    sc[j] = ws[WS_ATT + rg];
    PIN1(sc[j]);
  }
  PIN1(lbv); PIN1(l2v); PIN1(l2b);

  // ---- init LDS: zero all; 1.0 at bias A-slots (hi bufs, k=134,135) --------
  for (int p = tid; p < LDS_BYTES / 4; p += 512) ((float*)smraw)[p] = 0.f;
  __syncthreads();
  if (tid < 32) {
    int b = tid >> 4, r = tid & 15;
    *(unsigned short*)(smraw + b * HB_BYTES + 4096 + r * 16 + 12) = 0x3F80;
    *(unsigned short*)(smraw + b * HB_BYTES + 4096 + r * 16 + 14) = 0x3F80;
  }
  // xw_0 into buf1 kc4 (A(0) reads buf[(0-1)&1] = buf1)
  int pr = tid / 5, pd = tid - pr * 5;
  int prow = row0 + pr; if (prow > 2999) prow = 2999;
  const float* xw_row = xw_g + (size_t)prow * 320;
  if (tid < 80) {
    float v = xw_row[pd];
    float vh = (float)(__bf16)v;
    *(unsigned short*)(smraw + HB_BYTES + 4096 + pr * 16 + pd * 2) = bfbits(v);
    *(unsigned short*)(smraw + HB_BYTES + 5120 + 4096 + pr * 16 + pd * 2) = bfbits(v - vh);
  }
  __syncthreads();

  // per-lane h-write base (fragment-linear layout)
  int hi3 = (2 * w + (lc >> 3)) & 3;
  int hwbase = (w >> 1) * 1024 + hi3 * 256 + (lc & 7) * 2;

  bf16x8 ah[4];                 // carried hi A-frags of h_{t-1} (zero at t=0)
  f32x4 zf4 = {0.f, 0.f, 0.f, 0.f};
#pragma unroll
  for (int kc = 0; kc < 4; kc++) ah[kc] = __builtin_bit_cast(bf16x8, zf4);
  float cst[4] = {0.f, 0.f, 0.f, 0.f};

#pragma unroll 1
  for (int t = 0; t < T_STEPS; t++) {
    char* bufcur  = smraw + (t & 1) * HB_BYTES;
    char* bufprev = smraw + ((t & 1) ^ 1) * HB_BYTES;

    // prefetch xw_{t+1} (written to bufcur.kc4 after B2)
    float xnext = 0.f;
    if (tid < 80) {
      int tn = t + 1 < T_STEPS ? t + 1 : T_STEPS - 1;
      xnext = xw_row[tn * 5 + pd];
    }

    // ---- Phase A: z = [h|xw|1] @ [Whh;Wih;b]  (pure MFMA, bf16 split) -----
    f32x4 acc[4];
#pragma unroll
    for (int g = 0; g < 4; g++) acc[g] = zf4;
#pragma unroll
    for (int kc = 0; kc < 4; kc++) {
      bf16x8 alt = *(const bf16x8*)(bufprev + 5120 + kc * 1024 + lane * 16);
#pragma unroll
      for (int g = 0; g < 4; g++)
        acc[g] = __builtin_amdgcn_mfma_f32_16x16x32_bf16(ah[kc], bwh[g][kc], acc[g], 0, 0, 0);
#pragma unroll
      for (int g = 0; g < 4; g++)
        acc[g] = __builtin_amdgcn_mfma_f32_16x16x32_bf16(ah[kc], bwl[g][kc], acc[g], 0, 0, 0);
#pragma unroll
      for (int g = 0; g < 4; g++)
        acc[g] = __builtin_amdgcn_mfma_f32_16x16x32_bf16(alt, bwh[g][kc], acc[g], 0, 0, 0);
    }
    {
      bf16x8 a4h = *(const bf16x8*)(bufprev + 4096 + lane * 16);
      bf16x8 a4l = *(const bf16x8*)(bufprev + 5120 + 4096 + lane * 16);
#pragma unroll
      for (int g = 0; g < 4; g++)
        acc[g] = __builtin_amdgcn_mfma_f32_16x16x32_bf16(a4h, bih[g], acc[g], 0, 0, 0);
#pragma unroll
      for (int g = 0; g < 4; g++)
        acc[g] = __builtin_amdgcn_mfma_f32_16x16x32_bf16(a4l, bih[g], acc[g], 0, 0, 0);
    }

    // ---- gates (z fully in registers: acc[0..3] = i,f,g,o for 4 rows) -----
    float hval[4];
#pragma unroll
    for (int j = 0; j < 4; j++) {
      float ig = sigf(acc[0][j]), fg = sigf(acc[1][j]);
      float gg = tanhfast(acc[2][j]), og = sigf(acc[3][j]);
      float cn = fmaf(fg, cst[j], ig * gg);
      float hn = og * tanhfast(cn);
      cst[j] = cn; hval[j] = hn;
      float hh = (float)(__bf16)hn;
      *(unsigned short*)(bufcur + hwbase + (lg * 4 + j) * 16) = bfbits(hn);
      *(unsigned short*)(bufcur + 5120 + hwbase + (lg * 4 + j) * 16) = bfbits(hn - hh);
    }
    if (t == T_STEPS - 1) {
#pragma unroll
      for (int j = 0; j < 4; j++) {
        int r = lg * 4 + j;
        if (r < 12) {
          out[OUT_HT + (size_t)(row0 + r) * R + hcol] = hval[j];
          out[OUT_CT + (size_t)(row0 + r) * R + hcol] = cst[j];
        }
      }
    }
    __syncthreads();   // B2: h_t visible

    if (tid < 80) {
      float vh = (float)(__bf16)xnext;
      *(unsigned short*)(bufcur + 4096 + pr * 16 + pd * 2) = bfbits(xnext);
      *(unsigned short*)(bufcur + 5120 + 4096 + pr * 16 + pd * 2) = bfbits(xnext - vh);
    }

    // ---- Phase C: head G = h_t @ lin_w; frags carried into A(t+1) ---------
#pragma unroll
    for (int kc = 0; kc < 4; kc++)
      ah[kc] = *(const bf16x8*)(bufcur + kc * 1024 + lane * 16);
    f32x4 ga = zf4, gb = zf4;
    ga = __builtin_amdgcn_mfma_f32_16x16x32_bf16(ah[0], lh[0], ga, 0, 0, 0);
    ga = __builtin_amdgcn_mfma_f32_16x16x32_bf16(ah[0], ll[0], ga, 0, 0, 0);
    ga = __builtin_amdgcn_mfma_f32_16x16x32_bf16(ah[1], lh[1], ga, 0, 0, 0);
    ga = __builtin_amdgcn_mfma_f32_16x16x32_bf16(ah[1], ll[1], ga, 0, 0, 0);
    gb = __builtin_amdgcn_mfma_f32_16x16x32_bf16(ah[2], lh[2], gb, 0, 0, 0);
    gb = __builtin_amdgcn_mfma_f32_16x16x32_bf16(ah[2], ll[2], gb, 0, 0, 0);
    gb = __builtin_amdgcn_mfma_f32_16x16x32_bf16(ah[3], lh[3], gb, 0, 0, 0);
    gb = __builtin_amdgcn_mfma_f32_16x16x32_bf16(ah[3], ll[3], gb, 0, 0, 0);

#pragma unroll
    for (int j = 0; j < 4; j++) {
      float val = leakyf(fmaf(sc[j], ga[j] + gb[j], lbv)) * l2v;
      val += __shfl_xor(val, 1, 64);
      val += __shfl_xor(val, 2, 64);
      val += __shfl_xor(val, 4, 64);
      val += __shfl_xor(val, 8, 64);
      if (lc == 0)
        *(float*)(smraw + PART_OFF + ((lg * 4 + j) * 8 + w) * 4) = val;
    }
    __syncthreads();   // B3: partials visible

    if (tid < 12) {
      const float* pp = (const float*)(smraw + PART_OFF) + tid * 8;
      float s = l2b;
#pragma unroll
      for (int p = 0; p < 8; p++) s += pp[p];
      out[OUT_Y + (size_t)(row0 + tid) * T_STEPS + t] = s;
    }
  }
}

// ---------------------------------------------------------------------------
extern "C" void kernel_launch(void* const* d_in, const int* in_sizes, int n_in,
                              void* d_out, int out_size, void* d_ws, size_t ws_size,
                              hipStream_t stream) {
  const float* dynamic = (const float*)d_in[0];
  const float* pop     = (const float*)d_in[1];
  const float* demo    = (const float*)d_in[2];
  const float* eco     = (const float*)d_in[3];
  const float* geo     = (const float*)d_in[4];
  const float* W_pop   = (const float*)d_in[5];
  const float* a_pop   = (const float*)d_in[6];
  const float* W_demo  = (const float*)d_in[7];
  const float* a_demo  = (const float*)d_in[8];
  const float* W_eco   = (const float*)d_in[9];
  const float* a_eco   = (const float*)d_in[10];
  const float* W_geo   = (const float*)d_in[11];
  const float* a_geo   = (const float*)d_in[12];
  const float* cw_w1   = (const float*)d_in[13];
  const float* cw_b1   = (const float*)d_in[14];
  const float* cw_w2   = (const float*)d_in[15];
  const float* cw_b2   = (const float*)d_in[16];
  const float* hw_w1   = (const float*)d_in[17];
  const float* hw_b1   = (const float*)d_in[18];
  const float* hw_w2   = (const float*)d_in[19];
  const float* hw_b2   = (const float*)d_in[20];
  const float* Wih     = (const float*)d_in[21];
  const float* Whh     = (const float*)d_in[22];
  const float* b_lstm  = (const float*)d_in[23];
  const float* lin_w   = (const float*)d_in[24];
  const float* lin_b   = (const float*)d_in[25];
  const float* lin2_w  = (const float*)d_in[26];
  const float* lin2_b  = (const float*)d_in[27];

  float* out = (float*)d_out;
  float* ws  = (float*)d_ws;
  unsigned short* wsu = (unsigned short*)(ws + WS_PACK_F);

  pack_kernel<<<384, 256, 0, stream>>>(Whh, lin_w, Wih, b_lstm, wsu);
  scores_kernel<<<12, 256, 0, stream>>>(pop, demo, eco, W_pop, a_pop,
                                        W_demo, a_demo, W_eco, a_eco,
                                        W_geo, a_geo, ws);
  weights_kernel<<<750, 256, 0, stream>>>(dynamic, cw_w1, cw_b1, cw_w2, cw_b2,
                                          hw_w1, hw_b1, hw_w2, hw_b2, out, ws);
  dist_kernel<<<N_NODES, 256, 0, stream>>>(geo, out, ws);
  lstm_kernel<<<NBLK, 512, 0, stream>>>(wsu, ws, lin_b, lin2_w, lin2_b, out);
}

// Round 4
// 311.941 us; speedup vs baseline: 3.8812x; 1.3075x over previous
//
#include <hip/hip_runtime.h>
#include <hip/hip_bf16.h>

#define N_NODES 3000
#define T_STEPS 64
#define POP     16
#define DEMO    32
#define ECO     16
#define R       128
#define SLOPE   0.01f

#define NBLK    250      // 12 real rows per block, 16-row MFMA tile

// ---- workspace layout (floats) ----
#define WS_S1P 0
#define WS_S1D 3000
#define WS_S1E 6000
#define WS_S2P 9000
#define WS_S2D 12000
#define WS_S2E 15000
#define WS_GV  18000
#define WS_ATT 18432      // 3000
#define WS_XW  21504      // N*T*5 = 960000
#define WS_PACK_F 981504  // packed MFMA fragments (as ushort)
// pack region (ushort offsets in wsu):
//   [0,65536)        Whh hi frags   (ct 0..31, kc 0..3)
//   [65536,131072)   Whh lo frags
//   [131072,147456)  lin_w hi frags (ct 0..7, kc 0..3)
//   [147456,163840)  lin_w lo frags
//   [163840,180224)  Wih+bias frags (ct 0..31, kc4): k-slots 0..4=Wih_hi,
//                    5=0, 6=b_lo, 7=b_hi (A-side supplies 1.0 at slots 6,7)

// ---- output layout (floats) ----
#define OUT_Y    0
#define OUT_DIST 192000
#define OUT_TW   9192000
#define OUT_HT   10152000
#define OUT_CT   10536000

typedef __bf16 bf16x8 __attribute__((ext_vector_type(8)));
typedef float  f32x4  __attribute__((ext_vector_type(4)));

// rcpf: single v_rcp_f32 (1 ulp). Plain 1.0f/x without fast-math emits the
// full div_scale/div_fmas/div_fixup sequence (~10 ops) — round-3's hidden cost.
__device__ __forceinline__ float sigf(float x) {
  return __builtin_amdgcn_rcpf(1.0f + __expf(-x));
}
__device__ __forceinline__ float leakyf(float x) { return x >= 0.0f ? x : SLOPE * x; }
// overflow-safe tanh: 1 - 2/(e^{2x}+1)
__device__ __forceinline__ float tanhfast(float x) {
  return fmaf(-2.0f, __builtin_amdgcn_rcpf(__expf(2.0f * x) + 1.0f), 1.0f);
}
__device__ __forceinline__ unsigned short bfbits(float v) {
  __bf16 b = (__bf16)v;
  return __builtin_bit_cast(unsigned short, b);
}
// DPP-based add within 16-lane rows (pure VALU, no DS pipe, no LDS latency)
template <int CTRL>
__device__ __forceinline__ float dppsum(float v) {
  int p = __builtin_amdgcn_update_dpp(0, __builtin_bit_cast(int, v), CTRL, 0xF, 0xF, true);
  return v + __builtin_bit_cast(float, p);
}

// pin a fragment in VGPRs: asm "defines" the value -> no rematerialization
#define PIN4(x) { f32x4 _t = __builtin_bit_cast(f32x4, x); \
                  asm volatile("" : "+v"(_t)); \
                  x = __builtin_bit_cast(bf16x8, _t); }
#define PIN1(x) asm volatile("" : "+v"(x))

// ---------------------------------------------------------------------------
// Kernel 0: pack Whh, lin_w, Wih+bias into MFMA B-fragment layout (bf16 hi/lo)
// B-frag 16x16x32: lane l elem i -> B[k=kc*32+(l>>4)*8+i][n=ct*16+(l&15)]
// ---------------------------------------------------------------------------
__global__ __launch_bounds__(256) void pack_kernel(
    const float* __restrict__ Whh, const float* __restrict__ lin_w,
    const float* __restrict__ Wih, const float* __restrict__ b_lstm,
    unsigned short* __restrict__ wsu)
{
  int idx = blockIdx.x * 256 + threadIdx.x;   // 384*256 = 98304 exact
  if (idx < 65536) {
    int i = idx & 7, lane = (idx >> 3) & 63, kc = (idx >> 9) & 3, ct = idx >> 11;
    int k = kc * 32 + ((lane >> 4) << 3) + i;
    int n = ct * 16 + (lane & 15);
    float v = Whh[k * 512 + n];
    float hi = (float)(__bf16)v;
    wsu[idx]         = bfbits(v);
    wsu[65536 + idx] = bfbits(v - hi);
  } else if (idx < 81920) {
    int q = idx - 65536;                       // < 16384
    int i = q & 7, lane = (q >> 3) & 63, kc = (q >> 9) & 3, ct = q >> 11;
    int k = kc * 32 + ((lane >> 4) << 3) + i;
    int n = ct * 16 + (lane & 15);
    float v = lin_w[k * R + n];
    float hi = (float)(__bf16)v;
    wsu[131072 + q] = bfbits(v);
    wsu[147456 + q] = bfbits(v - hi);
  } else {
    int q = idx - 81920;                       // < 16384
    int i = q & 7, lane = (q >> 3) & 63, ct = q >> 9;   // ct 0..31
    int ks = ((lane >> 4) << 3) + i;           // k-slot within kc4 (0..31)
    int n = ct * 16 + (lane & 15);
    unsigned short o = 0;
    if (ks < 5) {
      o = bfbits(Wih[ks * 512 + n]);
    } else if (ks == 6) {
      float b = b_lstm[n];
      o = bfbits(b - (float)(__bf16)b);        // bias lo
    } else if (ks == 7) {
      o = bfbits(b_lstm[n]);                   // bias hi
    }
    wsu[163840 + q] = o;
  }
}

// ---------------------------------------------------------------------------
// Kernel 1: per-node pair-score vectors (unchanged)
// ---------------------------------------------------------------------------
__global__ __launch_bounds__(256) void scores_kernel(
    const float* __restrict__ pop,  const float* __restrict__ demo,
    const float* __restrict__ eco,
    const float* __restrict__ W_pop,  const float* __restrict__ a_pop,
    const float* __restrict__ W_demo, const float* __restrict__ a_demo,
    const float* __restrict__ W_eco,  const float* __restrict__ a_eco,
    const float* __restrict__ W_geo,  const float* __restrict__ a_geo,
    float* __restrict__ ws)
{
  int i = blockIdx.x * blockDim.x + threadIdx.x;
  if (i == 0) {
    float a0 = a_geo[0], a1 = a_geo[1];
    ws[WS_GV + 0] = W_geo[0] * a0 + W_geo[1] * a1;
    ws[WS_GV + 1] = W_geo[2] * a0 + W_geo[3] * a1;
  }
  if (i >= N_NODES) return;
  {
    float x[POP];
#pragma unroll
    for (int k = 0; k < POP; k++) x[k] = pop[i * POP + k];
    float s1 = 0.f, s2 = 0.f;
#pragma unroll
    for (int r = 0; r < POP; r++) {
      float h = 0.f;
#pragma unroll
      for (int k = 0; k < POP; k++) h = fmaf(x[k], W_pop[k * POP + r], h);
      s1 = fmaf(h, a_pop[r], s1);
      s2 = fmaf(h, a_pop[POP + r], s2);
    }
    ws[WS_S1P + i] = s1; ws[WS_S2P + i] = s2;
  }
  {
    float x[DEMO];
#pragma unroll
    for (int k = 0; k < DEMO; k++) x[k] = demo[i * DEMO + k];
    float s1 = 0.f, s2 = 0.f;
#pragma unroll 4
    for (int r = 0; r < DEMO; r++) {
      float h = 0.f;
#pragma unroll
      for (int k = 0; k < DEMO; k++) h = fmaf(x[k], W_demo[k * DEMO + r], h);
      s1 = fmaf(h, a_demo[r], s1);
      s2 = fmaf(h, a_demo[DEMO + r], s2);
    }
    ws[WS_S1D + i] = s1; ws[WS_S2D + i] = s2;
  }
  {
    float x[ECO];
#pragma unroll
    for (int k = 0; k < ECO; k++) x[k] = eco[i * ECO + k];
    float s1 = 0.f, s2 = 0.f;
#pragma unroll
    for (int r = 0; r < ECO; r++) {
      float h = 0.f;
#pragma unroll
      for (int k = 0; k < ECO; k++) h = fmaf(x[k], W_eco[k * ECO + r], h);
      s1 = fmaf(h, a_eco[r], s1);
      s2 = fmaf(h, a_eco[ECO + r], s2);
    }
    ws[WS_S1E + i] = s1; ws[WS_S2E + i] = s2;
  }
}

// ---------------------------------------------------------------------------
// Kernel 2: gate MLPs (rcp-based sigmoid)
// ---------------------------------------------------------------------------
__global__ __launch_bounds__(256) void weights_kernel(
    const float* __restrict__ dyn,
    const float* __restrict__ cw_w1, const float* __restrict__ cw_b1,
    const float* __restrict__ cw_w2, const float* __restrict__ cw_b2,
    const float* __restrict__ hw_w1, const float* __restrict__ hw_b1,
    const float* __restrict__ hw_w2, const float* __restrict__ hw_b2,
    float* __restrict__ out, float* __restrict__ ws)
{
  __shared__ float s_cw1[R], s_cb1[R], s_cw2[R], s_hb1[R];
  __shared__ float s_hw1[4 * R], s_hw2[R * 4];
  int tid = threadIdx.x;
  if (tid < R) {
    s_cw1[tid] = cw_w1[tid]; s_cb1[tid] = cw_b1[tid];
    s_cw2[tid] = cw_w2[tid]; s_hb1[tid] = hw_b1[tid];
  }
  for (int i = tid; i < 4 * R; i += 256) { s_hw1[i] = hw_w1[i]; s_hw2[i] = hw_w2[i]; }
  __syncthreads();

  int idx = blockIdx.x * 256 + tid;
  float x0 = dyn[idx * 5 + 0], x1 = dyn[idx * 5 + 1], x2 = dyn[idx * 5 + 2];
  float x3 = dyn[idx * 5 + 3], x4 = dyn[idx * 5 + 4];

  float acc = 0.f, o0 = 0.f, o1 = 0.f, o2 = 0.f, o3 = 0.f;
#pragma unroll 8
  for (int r = 0; r < R; r++) {
    float u = leakyf(fmaf(x0, s_cw1[r], s_cb1[r]));
    acc = fmaf(u, s_cw2[r], acc);
    float v = s_hb1[r];
    v = fmaf(x1, s_hw1[r], v);
    v = fmaf(x2, s_hw1[R + r], v);
    v = fmaf(x3, s_hw1[2 * R + r], v);
    v = fmaf(x4, s_hw1[3 * R + r], v);
    v = leakyf(v);
    o0 = fmaf(v, s_hw2[r * 4 + 0], o0);
    o1 = fmaf(v, s_hw2[r * 4 + 1], o1);
    o2 = fmaf(v, s_hw2[r * 4 + 2], o2);
    o3 = fmaf(v, s_hw2[r * 4 + 3], o3);
  }
  float tw0 = sigf(acc + cw_b2[0]);
  float tw1 = sigf(o0 + hw_b2[0]);
  float tw2 = sigf(o1 + hw_b2[1]);
  float tw3 = sigf(o2 + hw_b2[2]);
  float tw4 = sigf(o3 + hw_b2[3]);

  out[OUT_TW + idx * 5 + 0] = tw0;
  out[OUT_TW + idx * 5 + 1] = tw1;
  out[OUT_TW + idx * 5 + 2] = tw2;
  out[OUT_TW + idx * 5 + 3] = tw3;
  out[OUT_TW + idx * 5 + 4] = tw4;

  ws[WS_XW + idx * 5 + 0] = tw0 * x0;
  ws[WS_XW + idx * 5 + 1] = tw1 * x1;
  ws[WS_XW + idx * 5 + 2] = tw2 * x2;
  ws[WS_XW + idx * 5 + 3] = tw3 * x3;
  ws[WS_XW + idx * 5 + 4] = tw4 * x4;
}

// ---------------------------------------------------------------------------
// Kernel 3: dist rows + att_scale (rcp-based sigmoid, statically-indexed vals)
// ---------------------------------------------------------------------------
__global__ __launch_bounds__(256) void dist_kernel(
    const float* __restrict__ geo, float* __restrict__ out, float* __restrict__ ws)
{
  int i = blockIdx.x;
  int tid = threadIdx.x;
  __shared__ float sm[20];

  float s1p = ws[WS_S1P + i], s1d = ws[WS_S1D + i], s1e = ws[WS_S1E + i];
  float gv0 = ws[WS_GV + 0], gv1 = ws[WS_GV + 1];

  float vals[12];
  float vmax = -3.0e38f;
#pragma unroll
  for (int u = 0; u < 12; u++) {
    int j = tid + u * 256;
    float v = -3.0e38f;
    if (j < N_NODES) {
      float2 g = *(const float2*)&geo[((size_t)i * N_NODES + j) * 2];
      v = sigf(s1p + ws[WS_S2P + j]) + sigf(s1d + ws[WS_S2D + j]) +
          sigf(s1e + ws[WS_S2E + j]) + sigf(fmaf(g.x, gv0, g.y * gv1));
    }
    vals[u] = v;
    vmax = fmaxf(vmax, v);
  }
  int wid = tid >> 6, lane = tid & 63;
  for (int off = 32; off; off >>= 1) vmax = fmaxf(vmax, __shfl_down(vmax, off, 64));
  if (lane == 0) sm[wid] = vmax;
  __syncthreads();
  if (tid == 0) sm[8] = fmaxf(fmaxf(sm[0], sm[1]), fmaxf(sm[2], sm[3]));
  __syncthreads();
  vmax = sm[8];

  float lsum = 0.f;
#pragma unroll
  for (int u = 0; u < 12; u++) {
    int j = tid + u * 256;
    float e = (j < N_NODES) ? __expf(vals[u] - vmax) : 0.f;
    vals[u] = e;
    lsum += e;
  }
  for (int off = 32; off; off >>= 1) lsum += __shfl_down(lsum, off, 64);
  if (lane == 0) sm[4 + wid] = lsum;
  __syncthreads();
  if (tid == 0) sm[9] = sm[4] + sm[5] + sm[6] + sm[7];
  __syncthreads();
  float inv = __builtin_amdgcn_rcpf(sm[9]);

  float rs = 0.f;
#pragma unroll
  for (int u = 0; u < 12; u++) {
    int j = tid + u * 256;
    if (j < N_NODES) {
      float wv = vals[u] * inv;
      out[OUT_DIST + (size_t)i * N_NODES + j] = wv;
      rs += wv;
    }
  }
  for (int off = 32; off; off >>= 1) rs += __shfl_down(rs, off, 64);
  if (lane == 0) sm[10 + wid] = rs;
  __syncthreads();
  if (tid == 0) ws[WS_ATT + i] = 1.0f + (sm[10] + sm[11] + sm[12] + sm[13]);
}

// ---------------------------------------------------------------------------
// Kernel 4: persistent MFMA LSTM, bf16x2 Whh, 1 barrier/step, DPP head reduce.
// 250 blocks x 512 thr. Wave w, acc g covers z-cols g*128 + w*16 + lc.
// Double-buffered {h-hi | xw-hi | xw-lo} LDS (6KB each) + 2x PART (1KB).
// Head reduce of step t-1 runs in the MFMA shadow of step t's Phase A.
// ---------------------------------------------------------------------------
#define HB        6144    // per buffer: h-hi [0,4096) + xw-hi [4096,5120) + xw-lo [5120,6144)
#define XWH       4096
#define XWL       5120
#define PART_OFF  12288   // 2 parities x 16 rows x 8 waves f32 = 1024 B
#define LDS_BYTES 13312

__global__ __launch_bounds__(512, 2) void lstm_kernel(
    const unsigned short* __restrict__ wsu,
    const float* __restrict__ ws,
    const float* __restrict__ lin_b, const float* __restrict__ lin2_w,
    const float* __restrict__ lin2_b,
    float* __restrict__ out)
{
  __shared__ __align__(16) char smraw[LDS_BYTES];
  float* PARTf = (float*)(smraw + PART_OFF);
  int tid = threadIdx.x;
  int w = tid >> 6, lane = tid & 63;
  int lg = lane >> 4, lc = lane & 15;
  int row0 = blockIdx.x * 12;

  // ---- load + pin weight fragments (176 VGPRs, resident all 64 steps) -----
  bf16x8 bwh[4][4], bwl[4][4], bih[4], lh[4], ll[4];
#pragma unroll
  for (int g = 0; g < 4; g++) {
#pragma unroll
    for (int kc = 0; kc < 4; kc++) {
      int off = (((g * 8 + w) * 4 + kc) * 512) + lane * 8;
      bwh[g][kc] = *(const bf16x8*)(wsu + off);
      bwl[g][kc] = *(const bf16x8*)(wsu + 65536 + off);
      PIN4(bwh[g][kc]); PIN4(bwl[g][kc]);
    }
    bih[g] = *(const bf16x8*)(wsu + 163840 + (g * 8 + w) * 512 + lane * 8);
    PIN4(bih[g]);
  }
#pragma unroll
  for (int kc = 0; kc < 4; kc++) {
    int off = 131072 + (w * 4 + kc) * 512 + lane * 8;
    lh[kc] = *(const bf16x8*)(wsu + off);
    ll[kc] = *(const bf16x8*)(wsu + 16384 + off);
    PIN4(lh[kc]); PIN4(ll[kc]);
  }

  int hcol = w * 16 + lc;
  float lbv = lin_b[hcol], l2v = lin2_w[hcol], l2b = lin2_b[0];
  float sc[4];
#pragma unroll
  for (int j = 0; j < 4; j++) {
    int rg = row0 + lg * 4 + j; if (rg > 2999) rg = 2999;
    sc[j] = ws[WS_ATT + rg];
    PIN1(sc[j]);
  }
  PIN1(lbv); PIN1(l2v); PIN1(l2b);

  // ---- init LDS ----
  for (int p = tid; p < LDS_BYTES / 4; p += 512) ((float*)smraw)[p] = 0.f;
  __syncthreads();
  if (tid < 32) {   // 1.0 at bias A-slots (k=6,7 of kc4) in BOTH buffers' xw-hi
    int b = tid >> 4, r = tid & 15;
    *(unsigned short*)(smraw + b * HB + XWH + r * 16 + 12) = 0x3F80;
    *(unsigned short*)(smraw + b * HB + XWH + r * 16 + 14) = 0x3F80;
  }
  int pr = tid / 5, pd = tid - pr * 5;
  int prow = row0 + pr; if (prow > 2999) prow = 2999;
  const float* xw_row = ws + WS_XW + (size_t)prow * 320;
  if (tid < 80) {   // xw(0) -> buf0 (read by Phase A at t=0)
    float v = xw_row[pd];
    float vh = (float)(__bf16)v;
    *(unsigned short*)(smraw + XWH + pr * 16 + pd * 2) = bfbits(v);
    *(unsigned short*)(smraw + XWL + pr * 16 + pd * 2) = bfbits(v - vh);
  }
  __syncthreads();

  // per-lane h-write base (fragment-linear layout, hi only)
  int hi3 = (2 * w + (lc >> 3)) & 3;
  int hwbase = (w >> 1) * 1024 + hi3 * 256 + (lc & 7) * 2;

  bf16x8 ah[4];                 // h_{t-1} hi A-frags, carried in registers
  f32x4 zf4 = {0.f, 0.f, 0.f, 0.f};
#pragma unroll
  for (int kc = 0; kc < 4; kc++) ah[kc] = __builtin_bit_cast(bf16x8, zf4);
  float cst[4] = {0.f, 0.f, 0.f, 0.f};
  float val[4] = {0.f, 0.f, 0.f, 0.f};

#pragma unroll 1
  for (int t = 0; t < T_STEPS; t++) {
    char* bufcur = smraw + (t & 1) * HB;
    char* bufnxt = smraw + ((t & 1) ^ 1) * HB;

    // prefetch xw(t+1) from L2 (hidden under Phase A)
    float xnext = 0.f;
    if (tid < 80) {
      int tn = t + 1 < T_STEPS ? t + 1 : T_STEPS - 1;
      xnext = xw_row[tn * 5 + pd];
    }

    // ---- head reduce of step t-1 (DPP, fills Phase A's MFMA shadow) ------
    if (t > 0) {
#pragma unroll
      for (int j = 0; j < 4; j++) {
        float v = val[j];
        v = dppsum<0xB1>(v);    // xor1 (quad_perm 1,0,3,2)
        v = dppsum<0x4E>(v);    // xor2 (quad_perm 2,3,0,1)
        v = dppsum<0x141>(v);   // row_half_mirror
        v = dppsum<0x140>(v);   // row_mirror -> 16-lane row sum
        if (lc == 0) PARTf[((t - 1) & 1) * 128 + (lg * 4 + j) * 8 + w] = v;
      }
    }

    // ---- Phase A: z = [h|xw|1] @ [Whh;Wih;b]  (bf16x2: hi*hi + hi*lo) ----
    bf16x8 a4h = *(const bf16x8*)(bufcur + XWH + lane * 16);
    bf16x8 a4l = *(const bf16x8*)(bufcur + XWL + lane * 16);
    f32x4 acc[4];
#pragma unroll
    for (int g = 0; g < 4; g++) acc[g] = zf4;
#pragma unroll
    for (int kc = 0; kc < 4; kc++) {
#pragma unroll
      for (int g = 0; g < 4; g++)
        acc[g] = __builtin_amdgcn_mfma_f32_16x16x32_bf16(ah[kc], bwh[g][kc], acc[g], 0, 0, 0);
#pragma unroll
      for (int g = 0; g < 4; g++)
        acc[g] = __builtin_amdgcn_mfma_f32_16x16x32_bf16(ah[kc], bwl[g][kc], acc[g], 0, 0, 0);
    }
#pragma unroll
    for (int g = 0; g < 4; g++)
      acc[g] = __builtin_amdgcn_mfma_f32_16x16x32_bf16(a4h, bih[g], acc[g], 0, 0, 0);
#pragma unroll
    for (int g = 0; g < 4; g++)
      acc[g] = __builtin_amdgcn_mfma_f32_16x16x32_bf16(a4l, bih[g], acc[g], 0, 0, 0);

    // ---- gates (z in registers), write h-hi -> bufcur ---------------------
    float hval[4];
#pragma unroll
    for (int j = 0; j < 4; j++) {
      float ig = sigf(acc[0][j]), fg = sigf(acc[1][j]);
      float gg = tanhfast(acc[2][j]), og = sigf(acc[3][j]);
      float cn = fmaf(fg, cst[j], ig * gg);
      float hn = og * tanhfast(cn);
      cst[j] = cn; hval[j] = hn;
      *(unsigned short*)(bufcur + hwbase + (lg * 4 + j) * 16) = bfbits(hn);
    }
    if (tid < 80) {   // xw(t+1) -> other buffer (no reader until next barrier)
      float vh = (float)(__bf16)xnext;
      *(unsigned short*)(bufnxt + XWH + pr * 16 + pd * 2) = bfbits(xnext);
      *(unsigned short*)(bufnxt + XWL + pr * 16 + pd * 2) = bfbits(xnext - vh);
    }
    if (t == T_STEPS - 1) {
#pragma unroll
      for (int j = 0; j < 4; j++) {
        int r = lg * 4 + j;
        if (r < 12) {
          out[OUT_HT + (size_t)(row0 + r) * R + hcol] = hval[j];
          out[OUT_CT + (size_t)(row0 + r) * R + hcol] = cst[j];
        }
      }
    }
    __syncthreads();   // the ONLY barrier per step

    // ---- y(t-1) final sum (overlaps Phase C) ------------------------------
    if (t > 0 && tid < 12) {
      const float* pp = PARTf + ((t - 1) & 1) * 128 + tid * 8;
      float s = l2b;
#pragma unroll
      for (int p = 0; p < 8; p++) s += pp[p];
      out[OUT_Y + (size_t)(row0 + tid) * T_STEPS + (t - 1)] = s;
    }

    // ---- Phase C: G = h_t @ lin_w; A-frags carried into next Phase A ------
#pragma unroll
    for (int kc = 0; kc < 4; kc++)
      ah[kc] = *(const bf16x8*)(bufcur + kc * 1024 + lane * 16);
    f32x4 ga = zf4, gb = zf4;
    ga = __builtin_amdgcn_mfma_f32_16x16x32_bf16(ah[0], lh[0], ga, 0, 0, 0);
    ga = __builtin_amdgcn_mfma_f32_16x16x32_bf16(ah[0], ll[0], ga, 0, 0, 0);
    ga = __builtin_amdgcn_mfma_f32_16x16x32_bf16(ah[1], lh[1], ga, 0, 0, 0);
    ga = __builtin_amdgcn_mfma_f32_16x16x32_bf16(ah[1], ll[1], ga, 0, 0, 0);
    gb = __builtin_amdgcn_mfma_f32_16x16x32_bf16(ah[2], lh[2], gb, 0, 0, 0);
    gb = __builtin_amdgcn_mfma_f32_16x16x32_bf16(ah[2], ll[2], gb, 0, 0, 0);
    gb = __builtin_amdgcn_mfma_f32_16x16x32_bf16(ah[3], lh[3], gb, 0, 0, 0);
    gb = __builtin_amdgcn_mfma_f32_16x16x32_bf16(ah[3], ll[3], gb, 0, 0, 0);
#pragma unroll
    for (int j = 0; j < 4; j++)
      val[j] = leakyf(fmaf(sc[j], ga[j] + gb[j], lbv)) * l2v;
  }

  // ---- tail: y(63) ----
#pragma unroll
  for (int j = 0; j < 4; j++) {
    float v = val[j];
    v = dppsum<0xB1>(v); v = dppsum<0x4E>(v);
    v = dppsum<0x141>(v); v = dppsum<0x140>(v);
    if (lc == 0) PARTf[128 + (lg * 4 + j) * 8 + w] = v;   // parity 63&1 = 1
  }
  __syncthreads();
  if (tid < 12) {
    const float* pp = PARTf + 128 + tid * 8;
    float s = l2b;
#pragma unroll
    for (int p = 0; p < 8; p++) s += pp[p];
    out[OUT_Y + (size_t)(row0 + tid) * T_STEPS + 63] = s;
  }
}

// ---------------------------------------------------------------------------
extern "C" void kernel_launch(void* const* d_in, const int* in_sizes, int n_in,
                              void* d_out, int out_size, void* d_ws, size_t ws_size,
                              hipStream_t stream) {
  const float* dynamic = (const float*)d_in[0];
  const float* pop     = (const float*)d_in[1];
  const float* demo    = (const float*)d_in[2];
  const float* eco     = (const float*)d_in[3];
  const float* geo     = (const float*)d_in[4];
  const float* W_pop   = (const float*)d_in[5];
  const float* a_pop   = (const float*)d_in[6];
  const float* W_demo  = (const float*)d_in[7];
  const float* a_demo  = (const float*)d_in[8];
  const float* W_eco   = (const float*)d_in[9];
  const float* a_eco   = (const float*)d_in[10];
  const float* W_geo   = (const float*)d_in[11];
  const float* a_geo   = (const float*)d_in[12];
  const float* cw_w1   = (const float*)d_in[13];
  const float* cw_b1   = (const float*)d_in[14];
  const float* cw_w2   = (const float*)d_in[15];
  const float* cw_b2   = (const float*)d_in[16];
  const float* hw_w1   = (const float*)d_in[17];
  const float* hw_b1   = (const float*)d_in[18];
  const float* hw_w2   = (const float*)d_in[19];
  const float* hw_b2   = (const float*)d_in[20];
  const float* Wih     = (const float*)d_in[21];
  const float* Whh     = (const float*)d_in[22];
  const float* b_lstm  = (const float*)d_in[23];
  const float* lin_w   = (const float*)d_in[24];
  const float* lin_b   = (const float*)d_in[25];
  const float* lin2_w  = (const float*)d_in[26];
  const float* lin2_b  = (const float*)d_in[27];

  float* out = (float*)d_out;
  float* ws  = (float*)d_ws;
  unsigned short* wsu = (unsigned short*)(ws + WS_PACK_F);

  pack_kernel<<<384, 256, 0, stream>>>(Whh, lin_w, Wih, b_lstm, wsu);
  scores_kernel<<<12, 256, 0, stream>>>(pop, demo, eco, W_pop, a_pop,
                                        W_demo, a_demo, W_eco, a_eco,
                                        W_geo, a_geo, ws);
  weights_kernel<<<750, 256, 0, stream>>>(dynamic, cw_w1, cw_b1, cw_w2, cw_b2,
                                          hw_w1, hw_b1, hw_w2, hw_b2, out, ws);
  dist_kernel<<<N_NODES, 256, 0, stream>>>(geo, out, ws);
  lstm_kernel<<<NBLK, 512, 0, stream>>>(wsu, ws, lin_b, lin2_w, lin2_b, out);
}